// Round 7
// baseline (419.201 us; speedup 1.0000x reference)
//
#include <hip/hip_runtime.h>
#include <hip/hip_bf16.h>

typedef unsigned short ushort_t;
typedef unsigned int uint_t;

#define DD   128
#define G4   512
#define BT   16
#define NB   128
#define NV   32

// param block offsets (floats), each section 256-aligned so prep blocks map 1:1 to sources
#define OFF_WIH   0
#define OFF_EB    16384
#define OFF_PW    32768
#define OFF_PB    36864
#define OFF_INW   37120
#define OFF_INB   86272
#define OFF_OUTW  86784
#define OFF_OUTB  103168
#define OFF_IHB   103424
#define OFF_ICB   107520
#define OFF_DBIH  111616
#define OFF_DBHH  128000
#define OFF_DOW   144384
#define OFF_DOB   148480
#define P_TOTAL   148736   // = 581 * 256
// dtype flags stashed in PB-section padding: [32]=X, [33]=eWhh, [34]=iHw, [35]=iCw, [36]=dWhh
#define OFF_FLAGS (OFF_PB + 32)

typedef __attribute__((ext_vector_type(8))) short bf16x8;
typedef __attribute__((ext_vector_type(4))) float f32x4;

__device__ __forceinline__ float bf2f(ushort_t u) {
    union { uint_t i; float f; } x; x.i = ((uint_t)u) << 16; return x.f;
}
__device__ __forceinline__ ushort_t f2bf(float f) {
    __hip_bfloat16 h = __float2bfloat16(f);   // RNE
    return *(ushort_t*)&h;
}
__device__ __forceinline__ uint_t f2u(float f) {
    union { float f; uint_t i; } x; x.f = f; return x.i;
}
__device__ __forceinline__ float u2f(uint_t u) {
    union { uint_t i; float f; } x; x.i = u; return x.f;
}
// raw v_exp_f32 (2^x)
__device__ __forceinline__ float exp2_f(float x) {
    float r; asm("v_exp_f32 %0, %1" : "=v"(r) : "v"(x)); return r;
}
// sigmoid(x) = rcp(1 + 2^(-x*log2e))  -- saturates gracefully at both ends
__device__ __forceinline__ float sigmoid_f(float x) {
    return __builtin_amdgcn_rcpf(1.f + exp2_f(x * -1.442695041f));
}
// tanh(x) = 1 - 2*rcp(2^(2x*log2e)+1) -- saturates gracefully (rcp(inf)=0 -> 1)
__device__ __forceinline__ float tanh_f(float x) {
    return 1.f - 2.f * __builtin_amdgcn_rcpf(exp2_f(x * 2.885390082f) + 1.f);
}
// packed f32 -> 2x bf16 (RNE), guaranteed 1 instr
__device__ __forceinline__ uint_t cvt_pk_bf16(float a, float b) {
    uint_t r; asm("v_cvt_pk_bf16_f32 %0, %1, %2" : "=v"(r) : "v"(a), "v"(b)); return r;
}
__device__ __forceinline__ bf16x8 pack8(f32x4 a, f32x4 b) {
    union { uint_t u[4]; bf16x8 v; } x;
    x.u[0] = cvt_pk_bf16(a.x, a.y); x.u[1] = cvt_pk_bf16(a.z, a.w);
    x.u[2] = cvt_pk_bf16(b.x, b.y); x.u[3] = cvt_pk_bf16(b.z, b.w);
    return x.v;
}
__device__ __forceinline__ float swz_bcast_l15(float v) {
    // BitMode and=0x0F: new_lane = lane & 15 (within each 32-lane half)
    return u2f((uint_t)__builtin_amdgcn_ds_swizzle((int)f2u(v), 0x000F));
}
__device__ __forceinline__ void store_out(void* out, long idx, float v, int bf) {
    if (bf) ((ushort_t*)out)[idx] = f2bf(v);
    else    ((float*)out)[idx]    = v;
}
// light barrier: drain LDS only; global loads/stores stay in flight across it.
#define LBAR() do { asm volatile("s_waitcnt lgkmcnt(0)" ::: "memory"); \
                    __builtin_amdgcn_s_barrier(); } while (0)

// per-wave dtype probe: 1 if data looks bf16 when read as ushort
__device__ __forceinline__ int wave_probe(const void* p, int elems) {
    int cap = elems < 1024 ? elems : 1024;
    int lane = threadIdx.x & 63;
    const ushort_t* u = (const ushort_t*)p;
    int cnt = 0, tot = 0;
    for (int j = lane; j < cap; j += 64) {
        ushort_t x = u[j];
        float af = fabsf(bf2f(x));
        tot++;
        if (x == 0 || (af > 1e-7f && af < 100.f)) cnt++;
    }
    #pragma unroll
    for (int off = 32; off >= 1; off >>= 1) {
        cnt += __shfl_xor(cnt, off);
        tot += __shfl_xor(tot, off);
    }
    return (cnt * 10 >= tot * 9) ? 1 : 0;
}

struct Ptr19 { const void* p[19]; };

// ---------------- prep: params (581) + X transpose (256) + dtype flags (5) ----------------
__global__ __launch_bounds__(256) void prep_kernel(Ptr19 a, float* __restrict__ P,
                                                   float* __restrict__ Xc) {
    __shared__ float tile[32][65];
    if (blockIdx.x < 581) {
        int base = blockIdx.x * 256;
        int src, o0, size;
        if      (base < OFF_EB)   { src = 1;  o0 = base - OFF_WIH;  size = 16384; }
        else if (base < OFF_PW)   { src = 3;  o0 = base - OFF_EB;   size = 16384; }
        else if (base < OFF_PB)   { src = 4;  o0 = base - OFF_PW;   size = 4096;  }
        else if (base < OFF_INW)  { src = 5;  o0 = base - OFF_PB;   size = 32;    }
        else if (base < OFF_INB)  { src = 6;  o0 = base - OFF_INW;  size = 49152; }
        else if (base < OFF_OUTW) { src = 7;  o0 = base - OFF_INB;  size = 384;   }
        else if (base < OFF_OUTB) { src = 8;  o0 = base - OFF_OUTW; size = 16384; }
        else if (base < OFF_IHB)  { src = 9;  o0 = base - OFF_OUTB; size = 128;   }
        else if (base < OFF_ICB)  { src = 11; o0 = base - OFF_IHB;  size = 4096;  }
        else if (base < OFF_DBIH) { src = 13; o0 = base - OFF_ICB;  size = 4096;  }
        else if (base < OFF_DBHH) { src = 15; o0 = base - OFF_DBIH; size = 16384; }
        else if (base < OFF_DOW)  { src = 16; o0 = base - OFF_DBHH; size = 16384; }
        else if (base < OFF_DOB)  { src = 17; o0 = base - OFF_DOW;  size = 4096;  }
        else                      { src = 18; o0 = base - OFF_DOB;  size = 32;    }
        int bf = wave_probe(a.p[src], size);
        int off = o0 + (int)threadIdx.x;
        if (off < size)
            P[base + threadIdx.x] = bf ? bf2f(((const ushort_t*)a.p[src])[off])
                                       : ((const float*)a.p[src])[off];
    } else if (blockIdx.x < 837) {
        int bf = wave_probe(a.p[0], 1024);
        int idx2 = blockIdx.x - 581;
        int bt = (idx2 & 3) * 32, tn0 = (idx2 >> 2) * 64;
        const void* src = a.p[0];
        int tx = threadIdx.x & 63, ty = threadIdx.x >> 6;
        #pragma unroll
        for (int k = 0; k < 8; k++) {
            int row = ty * 8 + k;
            int idx = (bt + row) * 4096 + tn0 + tx;
            tile[row][tx] = bf ? bf2f(((const ushort_t*)src)[idx]) : ((const float*)src)[idx];
        }
        __syncthreads();
        int bx = threadIdx.x & 31, tyy = threadIdx.x >> 5;
        #pragma unroll
        for (int k = 0; k < 8; k++) {
            int tn = tn0 + tyy * 8 + k;
            int t = tn >> 5, nn = tn & 31;
            Xc[t * 4096 + nn * 128 + bt + bx] = tile[bx][tyy * 8 + k];
        }
    } else {
        int which = blockIdx.x - 837;            // 0..4
        int src = (which == 0) ? 0 : (which == 1) ? 2 : (which == 2) ? 10
                : (which == 3) ? 12 : 14;
        int flag = wave_probe(a.p[src], 1024);
        if (threadIdx.x == 0) P[OFF_FLAGS + which] = (float)flag;
    }
}

// ===================== encoder: operand-swapped MFMA recurrence =====================
// D[g-row][b-col]: thread owns (b = l15, d = 16w + 4quad + r, r=0..3).
// Pool-score consumption deferred one step (pend); h history in parity regs hpair[RB].
// Cell: proven saturating sigmoid/tanh (R5 best-known).
__global__ __launch_bounds__(512, 2) void enc_kernel(
    const float* __restrict__ Xc, const void* __restrict__ Wraw,
    const float* __restrict__ P, float* __restrict__ Cout)
{
    const int n = blockIdx.y, b0 = blockIdx.x * BT;
    const int tid = threadIdx.x;
    const int w = tid >> 6, lane = tid & 63;
    const int l15 = lane & 15, quad = lane >> 4;
    const int wbf = P[OFF_FLAGS + 1] > 0.5f;
    const int bown = b0 + l15;

    __shared__ alignas(16) ushort_t hS[2][16 * 136];
    for (int i = tid; i < 16 * 136; i += 512) hS[0][i] = 0;

    // A-fragments (weights): lane holds W[g = typ*128 + 16w + l15][k = 32kc+8quad+j]
    bf16x8 afrag[4][4];
    #pragma unroll
    for (int typ = 0; typ < 4; typ++) {
        const int g = typ * 128 + 16 * w + l15;
        #pragma unroll
        for (int kc = 0; kc < 4; kc++) {
            const int base = (n * G4 + g) * DD + 32 * kc + 8 * quad;
            if (wbf) {
                afrag[typ][kc] = *(const bf16x8*)((const ushort_t*)Wraw + base);
            } else {
                const float* fp = (const float*)Wraw + base;
                afrag[typ][kc] = pack8(*(const f32x4*)fp, *(const f32x4*)(fp + 4));
            }
        }
    }

    // pool A-fragment: rows 0 and 8 carry pw (so both 32-lane halves get s)
    bf16x8 pfrag[4];
    #pragma unroll
    for (int kc = 0; kc < 4; kc++) {
        bf16x8 tmp;
        #pragma unroll
        for (int j = 0; j < 8; j++)
            tmp[j] = (l15 == 0 || l15 == 8)
                   ? (short)f2bf(P[OFF_PW + n * DD + 32 * kc + 8 * quad + j]) : (short)0;
        pfrag[kc] = tmp;
    }

    f32x4 bias4[4], wih4[4];
    #pragma unroll
    for (int typ = 0; typ < 4; typ++) {
        int base = n * G4 + typ * 128 + 16 * w + 4 * quad;
        bias4[typ] = *(const f32x4*)&P[OFF_EB + base];
        wih4[typ]  = *(const f32x4*)&P[OFF_WIH + base];
    }
    const float pb_r = P[OFF_PB + n];
    const f32x4 pb4 = {pb_r, pb_r, pb_r, pb_r};

    float cst[4] = {0.f, 0.f, 0.f, 0.f};
    f32x4 hpair[2];
    hpair[0] = f32x4{0.f, 0.f, 0.f, 0.f};
    hpair[1] = f32x4{0.f, 0.f, 0.f, 0.f};
    f32x4 Cacc   = {0.f, 0.f, 0.f, 0.f};
    float lR = 0.f, pend = 0.f;

    const float* xnext = Xc + n * 128 + bown;
    float xq = *xnext;            // t = 0
    xnext += 4096;

    // static priority asymmetry: per SIMD one hi-prio and one lo-prio wave
    if (w & 4) __builtin_amdgcn_s_setprio(1);

#define ENC_STEP(T, RB)                                                              \
    do {                                                                             \
        LBAR();                                                                      \
        bf16x8 bh[4];                                                                \
        _Pragma("unroll")                                                            \
        for (int kc = 0; kc < 4; kc++)                                               \
            bh[kc] = *(const bf16x8*)&hS[RB][l15 * 136 + 32 * kc + 8 * quad];        \
        if ((T) >= 2) {   /* deferred pool update for h_{T-2} (in hpair[RB]) */      \
            float e = __expf(pend);                                                  \
            lR += e;                                                                 \
            f32x4 ev = {e, e, e, e};                                                 \
            Cacc += ev * hpair[RB];                                                  \
        }                                                                            \
        f32x4 xv = {xq, xq, xq, xq};                                                 \
        f32x4 acc[4];                                                                \
        _Pragma("unroll")                                                            \
        for (int typ = 0; typ < 4; typ++)                                            \
            acc[typ] = __builtin_amdgcn_mfma_f32_16x16x32_bf16(                      \
                afrag[typ][0], bh[0], bias4[typ] + xv * wih4[typ], 0, 0, 0);         \
        f32x4 accP = __builtin_amdgcn_mfma_f32_16x16x32_bf16(pfrag[0], bh[0], pb4, 0, 0, 0); \
        xq = *xnext; xnext += 4096;   /* over-read at T=126 stays inside Xc region */ \
        _Pragma("unroll")                                                            \
        for (int kc = 1; kc < 4; kc++) {                                             \
            accP = __builtin_amdgcn_mfma_f32_16x16x32_bf16(pfrag[kc], bh[kc], accP, 0, 0, 0); \
            _Pragma("unroll")                                                        \
            for (int typ = 0; typ < 4; typ++)                                        \
                acc[typ] = __builtin_amdgcn_mfma_f32_16x16x32_bf16(afrag[typ][kc], bh[kc], acc[typ], 0, 0, 0); \
        }                                                                            \
        if ((T) >= 1) pend = swz_bcast_l15(accP[0]);  /* score of h_{T-1}; latency hides under cell */ \
        float hh[4];                                                                 \
        _Pragma("unroll")                                                            \
        for (int r = 0; r < 4; r++) {                                                \
            float ii = sigmoid_f(acc[0][r]);                                         \
            float ff = sigmoid_f(acc[1][r]);                                         \
            float g2 = tanh_f(acc[2][r]);                                            \
            float oo = sigmoid_f(acc[3][r]);                                         \
            float cc = ff * cst[r] + ii * g2;                                        \
            cst[r] = cc;                                                             \
            hh[r] = oo * tanh_f(cc);                                                 \
        }                                                                            \
        hpair[RB].x = hh[0]; hpair[RB].y = hh[1];                                    \
        hpair[RB].z = hh[2]; hpair[RB].w = hh[3];                                    \
        uint2 hw;                                                                    \
        hw.x = cvt_pk_bf16(hh[0], hh[1]);                                            \
        hw.y = cvt_pk_bf16(hh[2], hh[3]);                                            \
        *(uint2*)&hS[(RB) ^ 1][l15 * 136 + 16 * w + 4 * quad] = hw;                  \
    } while (0)

    for (int tp = 0; tp < 63; tp++) {
        ENC_STEP(2 * tp, 0);
        ENC_STEP(2 * tp + 1, 1);
    }
    ENC_STEP(126, 0);
#undef ENC_STEP

    // final fold: consume pend(126)=score(h_125) with hpair[1]; then fresh score of
    // h_126 (in hS[1] / hpair[0]).
    LBAR();
    {
        float e = __expf(pend);
        lR += e;
        f32x4 ev = {e, e, e, e};
        Cacc += ev * hpair[1];

        f32x4 accP = __builtin_amdgcn_mfma_f32_16x16x32_bf16(
            pfrag[0], *(const bf16x8*)&hS[1][l15 * 136 + 8 * quad], pb4, 0, 0, 0);
        #pragma unroll
        for (int kc = 1; kc < 4; kc++) {
            bf16x8 bh = *(const bf16x8*)&hS[1][l15 * 136 + 32 * kc + 8 * quad];
            accP = __builtin_amdgcn_mfma_f32_16x16x32_bf16(pfrag[kc], bh, accP, 0, 0, 0);
        }
        float e2 = __expf(swz_bcast_l15(accP[0]));
        lR += e2;
        f32x4 ev2 = {e2, e2, e2, e2};
        Cacc += ev2 * hpair[0];
    }
    float inv = 1.f / lR;
    f32x4 iv = {inv, inv, inv, inv};
    f32x4 cv = Cacc * iv;
    *(f32x4*)&Cout[bown * (NV * DD) + n * DD + 16 * w + 4 * quad] = cv;
}

// ---------------- QKV projection ----------------
__global__ __launch_bounds__(256) void qkv_kernel(
    const float* __restrict__ C, const float* __restrict__ P,
    float* __restrict__ q, float* __restrict__ k, float* __restrict__ v)
{
    int b = blockIdx.x, p = blockIdx.y, tid = threadIdx.x;
    int j = tid & 127, half = tid >> 7;
    __shared__ float Cb[NV * DD];
    for (int i = tid; i < NV * DD; i += 256) Cb[i] = C[b * (NV * DD) + i];
    __syncthreads();

    const float* wrow = P + OFF_INW + (p * DD + j) * DD;
    float bias = P[OFF_INB + p * DD + j];
    float acc[16];
    #pragma unroll
    for (int nn = 0; nn < 16; nn++) acc[nn] = bias;

    for (int dc = 0; dc < DD; dc += 8) {
        float4 w0 = *(const float4*)&wrow[dc];
        float4 w1 = *(const float4*)&wrow[dc + 4];
        #pragma unroll
        for (int nn = 0; nn < 16; nn++) {
            const float* cb = &Cb[(half * 16 + nn) * DD + dc];
            float4 c0 = *(float4*)&cb[0];
            float4 c1 = *(float4*)&cb[4];
            acc[nn] += c0.x * w0.x + c0.y * w0.y + c0.z * w0.z + c0.w * w0.w
                     + c1.x * w1.x + c1.y * w1.y + c1.z * w1.z + c1.w * w1.w;
        }
    }
    float* dst = (p == 0) ? q : (p == 1) ? k : v;
    for (int nn = 0; nn < 16; nn++)
        dst[b * (NV * DD) + (half * 16 + nn) * DD + j] = acc[nn];
}

// ---------------- cross-attention + out-proj + residual, split by query-half ----------------
// K/V staging double-buffered through registers (T14): loads for tau+1 issue before
// compute(tau), so the ~500cy global latency hides under the dot-product work.
__global__ __launch_bounds__(128) void attn_kernel(
    const float* __restrict__ q, const float* __restrict__ k, const float* __restrict__ v,
    const float* __restrict__ C, const float* __restrict__ P,
    float* __restrict__ Cstar, void* __restrict__ dout)
{
    int b = blockIdx.x, half = blockIdx.y, tid = threadIdx.x;
    int obf = P[OFF_FLAGS + 0] > 0.5f;
    int n0 = half * 16;
    __shared__ float Qs[16 * DD], Ks[NV * DD], Vs[NV * DD];
    float* Os = Ks;   // reused after last Ks read (sync-separated)
    for (int i = tid; i < 16 * DD; i += 128) Qs[i] = q[b * (NV * DD) + n0 * DD + i];
    __syncthreads();

    int hh = tid >> 4, qi = tid & 15;   // 8 heads x 16 queries
    float qreg[16];
    #pragma unroll
    for (int u = 0; u < 4; u++) {
        float4 t4 = *(float4*)&Qs[qi * DD + hh * 16 + 4 * u];
        qreg[4*u] = t4.x; qreg[4*u+1] = t4.y; qreg[4*u+2] = t4.z; qreg[4*u+3] = t4.w;
    }

    float Oacc[16];
    #pragma unroll
    for (int u = 0; u < 16; u++) Oacc[u] = 0.f;
    float wsum = 0.f;
    int tmax = (b < 5) ? b : 5;

    // reg prefetch buffers: 8 float4 each (1024 float4 per array / 128 threads)
    float4 kr[8], vr[8];
#define ATT_LOAD(TAU)                                                            \
    do {                                                                         \
        const float4* kp = (const float4*)&k[(b - (TAU)) * (NV * DD)];           \
        const float4* vp = (const float4*)&v[(b - (TAU)) * (NV * DD)];           \
        _Pragma("unroll")                                                        \
        for (int u = 0; u < 8; u++) {                                            \
            kr[u] = kp[tid + 128 * u];                                           \
            vr[u] = vp[tid + 128 * u];                                           \
        }                                                                        \
    } while (0)

    if (tmax >= 1) ATT_LOAD(1);

    for (int tau = 1; tau <= tmax; tau++) {
        __syncthreads();
        #pragma unroll
        for (int u = 0; u < 8; u++) {
            ((float4*)Ks)[tid + 128 * u] = kr[u];
            ((float4*)Vs)[tid + 128 * u] = vr[u];
        }
        __syncthreads();
        if (tau < tmax) ATT_LOAD(tau + 1);   // issue next-tau loads; hide under compute

        float s[NV];
        #pragma unroll
        for (int kk = 0; kk < NV; kk++) {
            float a = 0.f;
            #pragma unroll
            for (int u = 0; u < 4; u++) {
                float4 kv = *(float4*)&Ks[kk * DD + hh * 16 + 4 * u];
                a += qreg[4*u] * kv.x + qreg[4*u+1] * kv.y
                   + qreg[4*u+2] * kv.z + qreg[4*u+3] * kv.w;
            }
            s[kk] = a * 0.25f;
        }
        float mm = s[0];
        #pragma unroll
        for (int kk = 1; kk < NV; kk++) mm = fmaxf(mm, s[kk]);
        float ssum = 0.f;
        #pragma unroll
        for (int kk = 0; kk < NV; kk++) { s[kk] = __expf(s[kk] - mm); ssum += s[kk]; }
        float wdk = __expf(-0.7f * (float)(tau - 1));
        wsum += wdk;
        float wr = wdk / ssum;
        #pragma unroll
        for (int u = 0; u < 4; u++) {
            float ax = 0.f, ay = 0.f, az = 0.f, aw = 0.f;
            #pragma unroll
            for (int kk = 0; kk < NV; kk++) {
                float4 vv = *(float4*)&Vs[kk * DD + hh * 16 + 4 * u];
                ax += s[kk] * vv.x; ay += s[kk] * vv.y;
                az += s[kk] * vv.z; aw += s[kk] * vv.w;
            }
            Oacc[4*u] += wr * ax; Oacc[4*u+1] += wr * ay;
            Oacc[4*u+2] += wr * az; Oacc[4*u+3] += wr * aw;
        }
    }
#undef ATT_LOAD

    __syncthreads();
    float winv = (b > 0) ? 1.f / wsum : 0.f;
    #pragma unroll
    for (int u = 0; u < 16; u++)
        Os[qi * DD + hh * 16 + u] = Oacc[u] * winv;   // Os rows = local queries 0..15
    __syncthreads();

    int j = tid;   // 0..127 output column
    const float* wrow = P + OFF_OUTW + j * DD;
    float obias = P[OFF_OUTB + j];
    for (int nn = 0; nn < 16; nn++) {
        float a = (b > 0) ? obias : 0.f;
        for (int dc = 0; dc < DD; dc += 8) {
            float4 w0 = *(const float4*)&wrow[dc];
            float4 w1 = *(const float4*)&wrow[dc + 4];
            float4 o0 = *(float4*)&Os[nn * DD + dc];
            float4 o1 = *(float4*)&Os[nn * DD + dc + 4];
            a += o0.x*w0.x + o0.y*w0.y + o0.z*w0.z + o0.w*w0.w
               + o1.x*w1.x + o1.y*w1.y + o1.z*w1.z + o1.w*w1.w;
        }
        int nng = n0 + nn;
        float cs = C[b * (NV * DD) + nng * DD + j] + a;
        Cstar[b * (NV * DD) + nng * DD + j] = cs;
        store_out(dout, 524288 + b * (NV * DD) + nng * DD + j, cs, obf);
    }
}

// ===================== decoder: fused init + operand-swapped MFMA recurrence =====================
__global__ __launch_bounds__(512, 2) void dec_kernel(
    const float* __restrict__ Cstar,
    const void* __restrict__ iHw, const void* __restrict__ iCw,
    const void* __restrict__ Wraw,
    const float* __restrict__ P, void* __restrict__ out)
{
    const int n = blockIdx.y, b0 = blockIdx.x * BT;
    const int tid = threadIdx.x;
    const int w = tid >> 6, lane = tid & 63;
    const int l15 = lane & 15, quad = lane >> 4;
    const int obf = P[OFF_FLAGS + 0] > 0.5f;
    const int hbf = P[OFF_FLAGS + 2] > 0.5f;
    const int cbf = P[OFF_FLAGS + 3] > 0.5f;
    const int wbf = P[OFF_FLAGS + 4] > 0.5f;
    const int bown = b0 + l15;

    __shared__ alignas(16) ushort_t hS[2][16 * 136];

    // ---- fused init: D[e-row][b-col] = Cst.W^T + b ----
    bf16x8 cstB[4];
    #pragma unroll
    for (int kc = 0; kc < 4; kc++) {
        const float* cp = &Cstar[bown * (NV * DD) + n * DD + 32 * kc + 8 * quad];
        cstB[kc] = pack8(*(const f32x4*)&cp[0], *(const f32x4*)&cp[4]);
    }
    float cst[4];
    {
        f32x4 hAcc = *(const f32x4*)&P[OFF_IHB + n * DD + 16 * w + 4 * quad];
        f32x4 cAcc = *(const f32x4*)&P[OFF_ICB + n * DD + 16 * w + 4 * quad];
        #pragma unroll
        for (int kc = 0; kc < 4; kc++) {
            const int base = (n * DD + 16 * w + l15) * DD + 32 * kc + 8 * quad;
            bf16x8 wA;
            if (hbf) wA = *(const bf16x8*)((const ushort_t*)iHw + base);
            else {
                const float* fp = (const float*)iHw + base;
                wA = pack8(*(const f32x4*)fp, *(const f32x4*)(fp + 4));
            }
            hAcc = __builtin_amdgcn_mfma_f32_16x16x32_bf16(wA, cstB[kc], hAcc, 0, 0, 0);
            if (cbf) wA = *(const bf16x8*)((const ushort_t*)iCw + base);
            else {
                const float* fp = (const float*)iCw + base;
                wA = pack8(*(const f32x4*)fp, *(const f32x4*)(fp + 4));
            }
            cAcc = __builtin_amdgcn_mfma_f32_16x16x32_bf16(wA, cstB[kc], cAcc, 0, 0, 0);
        }
        float h0 = tanh_f(hAcc[0]), h1 = tanh_f(hAcc[1]);
        float h2 = tanh_f(hAcc[2]), h3 = tanh_f(hAcc[3]);
        #pragma unroll
        for (int r = 0; r < 4; r++) cst[r] = tanh_f(cAcc[r]);
        uint2 hw;
        hw.x = cvt_pk_bf16(h0, h1);
        hw.y = cvt_pk_bf16(h2, h3);
        *(uint2*)&hS[0][l15 * 136 + 16 * w + 4 * quad] = hw;
    }

    // ---- recurrence weights (A-operand) ----
    bf16x8 afrag[4][4];
    #pragma unroll
    for (int typ = 0; typ < 4; typ++) {
        const int g = typ * 128 + 16 * w + l15;
        #pragma unroll
        for (int kc = 0; kc < 4; kc++) {
            const int base = (n * G4 + g) * DD + 32 * kc + 8 * quad;
            if (wbf) {
                afrag[typ][kc] = *(const bf16x8*)((const ushort_t*)Wraw + base);
            } else {
                const float* fp = (const float*)Wraw + base;
                afrag[typ][kc] = pack8(*(const f32x4*)fp, *(const f32x4*)(fp + 4));
            }
        }
    }

    // out-proj A-fragment: row 0 = ow (every wave holds it; out-proj rotates per step)
    bf16x8 pfrag[4];
    #pragma unroll
    for (int kc = 0; kc < 4; kc++) {
        bf16x8 tmp;
        #pragma unroll
        for (int j = 0; j < 8; j++)
            tmp[j] = (l15 == 0) ? (short)f2bf(P[OFF_DOW + n * DD + 32 * kc + 8 * quad + j]) : (short)0;
        pfrag[kc] = tmp;
    }

    f32x4 bias4[4];
    #pragma unroll
    for (int typ = 0; typ < 4; typ++) {
        int base = n * G4 + typ * 128 + 16 * w + 4 * quad;
        f32x4 b1 = *(const f32x4*)&P[OFF_DBIH + base];
        f32x4 b2 = *(const f32x4*)&P[OFF_DBHH + base];
        bias4[typ] = b1 + b2;
    }
    const float ob_r = P[OFF_DOB + n];
    const f32x4 ob4 = {ob_r, ob_r, ob_r, ob_r};

    // static priority asymmetry: per SIMD one hi-prio and one lo-prio wave
    if (w & 4) __builtin_amdgcn_s_setprio(1);

#define DEC_STEP(T, RB)                                                              \
    do {                                                                             \
        LBAR();                                                                      \
        bf16x8 bh[4];                                                                \
        _Pragma("unroll")                                                            \
        for (int kc = 0; kc < 4; kc++)                                               \
            bh[kc] = *(const bf16x8*)&hS[RB][l15 * 136 + 32 * kc + 8 * quad];        \
        f32x4 acc[4];                                                                \
        _Pragma("unroll")                                                            \
        for (int typ = 0; typ < 4; typ++)                                            \
            acc[typ] = __builtin_amdgcn_mfma_f32_16x16x32_bf16(afrag[typ][0], bh[0], bias4[typ], 0, 0, 0); \
        _Pragma("unroll")                                                            \
        for (int kc = 1; kc < 4; kc++)                                               \
            _Pragma("unroll")                                                        \
            for (int typ = 0; typ < 4; typ++)                                        \
                acc[typ] = __builtin_amdgcn_mfma_f32_16x16x32_bf16(afrag[typ][kc], bh[kc], acc[typ], 0, 0, 0); \
        if (w == ((T) & 7)) {   /* rotate out-proj wave to balance the extra work */ \
            f32x4 accP = __builtin_amdgcn_mfma_f32_16x16x32_bf16(pfrag[0], bh[0], ob4, 0, 0, 0); \
            _Pragma("unroll")                                                        \
            for (int kc = 1; kc < 4; kc++)                                           \
                accP = __builtin_amdgcn_mfma_f32_16x16x32_bf16(pfrag[kc], bh[kc], accP, 0, 0, 0); \
            if ((T) > 0 && quad == 0)                                                \
                store_out(out, (long)bown * 4064 + (long)((T) - 1) * NV + n, accP[0], obf); \
        }                                                                            \
        float hh[4];                                                                 \
        _Pragma("unroll")                                                            \
        for (int r = 0; r < 4; r++) {                                                \
            float ii = sigmoid_f(acc[0][r]);                                         \
            float ff = sigmoid_f(acc[1][r]);                                         \
            float g2 = tanh_f(acc[2][r]);                                            \
            float oo = sigmoid_f(acc[3][r]);                                         \
            float cc = ff * cst[r] + ii * g2;                                        \
            cst[r] = cc;                                                             \
            hh[r] = oo * tanh_f(cc);                                                 \
        }                                                                            \
        uint2 hw;                                                                    \
        hw.x = cvt_pk_bf16(hh[0], hh[1]);                                            \
        hw.y = cvt_pk_bf16(hh[2], hh[3]);                                            \
        *(uint2*)&hS[(RB) ^ 1][l15 * 136 + 16 * w + 4 * quad] = hw;                  \
    } while (0)

    for (int tp = 0; tp < 64; tp++) {
        DEC_STEP(2 * tp, 0);
        DEC_STEP(2 * tp + 1, 1);
    }
#undef DEC_STEP

    // o_127 from h_127 (t=127 wrote hS[0]); 128 & 7 == 0 -> wave 0, consistent with rotation
    LBAR();
    if (w == 0) {
        f32x4 accP = __builtin_amdgcn_mfma_f32_16x16x32_bf16(
            pfrag[0], *(const bf16x8*)&hS[0][l15 * 136 + 8 * quad], ob4, 0, 0, 0);
        #pragma unroll
        for (int kc = 1; kc < 4; kc++) {
            bf16x8 bh = *(const bf16x8*)&hS[0][l15 * 136 + 32 * kc + 8 * quad];
            accP = __builtin_amdgcn_mfma_f32_16x16x32_bf16(pfrag[kc], bh, accP, 0, 0, 0);
        }
        if (quad == 0)
            store_out(out, 520192 + (long)bown * NV + n, accP[0], obf);
    }
}

extern "C" void kernel_launch(void* const* d_in, const int* in_sizes, int n_in,
                              void* d_out, int out_size, void* d_ws, size_t ws_size,
                              hipStream_t stream) {
    char* ws = (char*)d_ws;
    float*    P    = (float*)(ws + 0);              // ~595 KB
    float*    Xc   = (float*)(ws + (1u << 20));     // 2 MB
    float*    C    = (float*)(ws + (3u << 20));     // 2 MB
    float*    qb   = (float*)(ws + (5u << 20));
    float*    kb   = (float*)(ws + (7u << 20));
    float*    vb   = (float*)(ws + (9u << 20));
    float*    Cst  = (float*)(ws + (11u << 20));

    Ptr19 a;
    for (int i = 0; i < 19; i++) a.p[i] = d_in[i];

    prep_kernel<<<842, 256, 0, stream>>>(a, P, Xc);
    enc_kernel<<<dim3(8, 32), 512, 0, stream>>>(Xc, d_in[2], P, C);
    qkv_kernel<<<dim3(128, 3), 256, 0, stream>>>(C, P, qb, kb, vb);
    attn_kernel<<<dim3(128, 2), 128, 0, stream>>>(qb, kb, vb, C, P, Cst, d_out);
    dec_kernel<<<dim3(8, 32), 512, 0, stream>>>(Cst, d_in[10], d_in[12], d_in[14], P, d_out);
}

// Round 8
// 412.746 us; speedup vs baseline: 1.0156x; 1.0156x over previous
//
#include <hip/hip_runtime.h>
#include <hip/hip_bf16.h>

typedef unsigned short ushort_t;
typedef unsigned int uint_t;

#define DD   128
#define G4   512
#define BT   16
#define NB   128
#define NV   32

// param block offsets (floats), each section 256-aligned so prep blocks map 1:1 to sources
#define OFF_WIH   0
#define OFF_EB    16384
#define OFF_PW    32768
#define OFF_PB    36864
#define OFF_INW   37120
#define OFF_INB   86272
#define OFF_OUTW  86784
#define OFF_OUTB  103168
#define OFF_IHB   103424
#define OFF_ICB   107520
#define OFF_DBIH  111616
#define OFF_DBHH  128000
#define OFF_DOW   144384
#define OFF_DOB   148480
#define P_TOTAL   148736   // = 581 * 256
// dtype flags stashed in PB-section padding: [32]=X, [33]=eWhh, [34]=iHw, [35]=iCw, [36]=dWhh
#define OFF_FLAGS (OFF_PB + 32)

typedef __attribute__((ext_vector_type(8))) short bf16x8;
typedef __attribute__((ext_vector_type(4))) float f32x4;

__device__ __forceinline__ float bf2f(ushort_t u) {
    union { uint_t i; float f; } x; x.i = ((uint_t)u) << 16; return x.f;
}
__device__ __forceinline__ ushort_t f2bf(float f) {
    __hip_bfloat16 h = __float2bfloat16(f);   // RNE
    return *(ushort_t*)&h;
}
__device__ __forceinline__ uint_t f2u(float f) {
    union { float f; uint_t i; } x; x.f = f; return x.i;
}
__device__ __forceinline__ float u2f(uint_t u) {
    union { uint_t i; float f; } x; x.i = u; return x.f;
}
// raw v_exp_f32 (2^x)
__device__ __forceinline__ float exp2_f(float x) {
    float r; asm("v_exp_f32 %0, %1" : "=v"(r) : "v"(x)); return r;
}
#define L1C (-1.442695041f)
#define L2C (2.885390082f)
// sigmoid(x) = rcp(1 + 2^(-x*log2e))  -- saturates gracefully at both ends
__device__ __forceinline__ float sigmoid_f(float x) {
    return __builtin_amdgcn_rcpf(1.f + exp2_f(x * L1C));
}
// tanh(x) = 1 - 2*rcp(2^(2x*log2e)+1) -- saturates gracefully (rcp(inf)=0 -> 1)
__device__ __forceinline__ float tanh_f(float x) {
    return 1.f - 2.f * __builtin_amdgcn_rcpf(exp2_f(x * L2C) + 1.f);
}
// packed f32 -> 2x bf16 (RNE), guaranteed 1 instr
__device__ __forceinline__ uint_t cvt_pk_bf16(float a, float b) {
    uint_t r; asm("v_cvt_pk_bf16_f32 %0, %1, %2" : "=v"(r) : "v"(a), "v"(b)); return r;
}
__device__ __forceinline__ bf16x8 pack8(f32x4 a, f32x4 b) {
    union { uint_t u[4]; bf16x8 v; } x;
    x.u[0] = cvt_pk_bf16(a.x, a.y); x.u[1] = cvt_pk_bf16(a.z, a.w);
    x.u[2] = cvt_pk_bf16(b.x, b.y); x.u[3] = cvt_pk_bf16(b.z, b.w);
    return x.v;
}
__device__ __forceinline__ float swz_bcast_l15(float v) {
    // BitMode and=0x0F: new_lane = lane & 15 (within each 32-lane half)
    return u2f((uint_t)__builtin_amdgcn_ds_swizzle((int)f2u(v), 0x000F));
}
__device__ __forceinline__ void store_out(void* out, long idx, float v, int bf) {
    if (bf) ((ushort_t*)out)[idx] = f2bf(v);
    else    ((float*)out)[idx]    = v;
}
// light barrier: drain LDS only; global loads/stores stay in flight across it.
#define LBAR() do { asm volatile("s_waitcnt lgkmcnt(0)" ::: "memory"); \
                    __builtin_amdgcn_s_barrier(); } while (0)

// per-wave dtype probe: 1 if data looks bf16 when read as ushort
__device__ __forceinline__ int wave_probe(const void* p, int elems) {
    int cap = elems < 1024 ? elems : 1024;
    int lane = threadIdx.x & 63;
    const ushort_t* u = (const ushort_t*)p;
    int cnt = 0, tot = 0;
    for (int j = lane; j < cap; j += 64) {
        ushort_t x = u[j];
        float af = fabsf(bf2f(x));
        tot++;
        if (x == 0 || (af > 1e-7f && af < 100.f)) cnt++;
    }
    #pragma unroll
    for (int off = 32; off >= 1; off >>= 1) {
        cnt += __shfl_xor(cnt, off);
        tot += __shfl_xor(tot, off);
    }
    return (cnt * 10 >= tot * 9) ? 1 : 0;
}

struct Ptr19 { const void* p[19]; };

// ---------------- prep: params (581) + X transpose (256) + dtype flags (5) ----------------
__global__ __launch_bounds__(256) void prep_kernel(Ptr19 a, float* __restrict__ P,
                                                   float* __restrict__ Xc) {
    __shared__ float tile[32][65];
    if (blockIdx.x < 581) {
        int base = blockIdx.x * 256;
        int src, o0, size;
        if      (base < OFF_EB)   { src = 1;  o0 = base - OFF_WIH;  size = 16384; }
        else if (base < OFF_PW)   { src = 3;  o0 = base - OFF_EB;   size = 16384; }
        else if (base < OFF_PB)   { src = 4;  o0 = base - OFF_PW;   size = 4096;  }
        else if (base < OFF_INW)  { src = 5;  o0 = base - OFF_PB;   size = 32;    }
        else if (base < OFF_INB)  { src = 6;  o0 = base - OFF_INW;  size = 49152; }
        else if (base < OFF_OUTW) { src = 7;  o0 = base - OFF_INB;  size = 384;   }
        else if (base < OFF_OUTB) { src = 8;  o0 = base - OFF_OUTW; size = 16384; }
        else if (base < OFF_IHB)  { src = 9;  o0 = base - OFF_OUTB; size = 128;   }
        else if (base < OFF_ICB)  { src = 11; o0 = base - OFF_IHB;  size = 4096;  }
        else if (base < OFF_DBIH) { src = 13; o0 = base - OFF_ICB;  size = 4096;  }
        else if (base < OFF_DBHH) { src = 15; o0 = base - OFF_DBIH; size = 16384; }
        else if (base < OFF_DOW)  { src = 16; o0 = base - OFF_DBHH; size = 16384; }
        else if (base < OFF_DOB)  { src = 17; o0 = base - OFF_DOW;  size = 4096;  }
        else                      { src = 18; o0 = base - OFF_DOB;  size = 32;    }
        int bf = wave_probe(a.p[src], size);
        int off = o0 + (int)threadIdx.x;
        if (off < size)
            P[base + threadIdx.x] = bf ? bf2f(((const ushort_t*)a.p[src])[off])
                                       : ((const float*)a.p[src])[off];
    } else if (blockIdx.x < 837) {
        int bf = wave_probe(a.p[0], 1024);
        int idx2 = blockIdx.x - 581;
        int bt = (idx2 & 3) * 32, tn0 = (idx2 >> 2) * 64;
        const void* src = a.p[0];
        int tx = threadIdx.x & 63, ty = threadIdx.x >> 6;
        #pragma unroll
        for (int k = 0; k < 8; k++) {
            int row = ty * 8 + k;
            int idx = (bt + row) * 4096 + tn0 + tx;
            tile[row][tx] = bf ? bf2f(((const ushort_t*)src)[idx]) : ((const float*)src)[idx];
        }
        __syncthreads();
        int bx = threadIdx.x & 31, tyy = threadIdx.x >> 5;
        #pragma unroll
        for (int k = 0; k < 8; k++) {
            int tn = tn0 + tyy * 8 + k;
            int t = tn >> 5, nn = tn & 31;
            Xc[t * 4096 + nn * 128 + bt + bx] = tile[bx][tyy * 8 + k];
        }
    } else {
        int which = blockIdx.x - 837;            // 0..4
        int src = (which == 0) ? 0 : (which == 1) ? 2 : (which == 2) ? 10
                : (which == 3) ? 12 : 14;
        int flag = wave_probe(a.p[src], 1024);
        if (threadIdx.x == 0) P[OFF_FLAGS + which] = (float)flag;
    }
}

// ===================== encoder: operand-swapped MFMA recurrence =====================
// D[g-row][b-col]: thread owns (b = l15, d = 16w + 4quad + r, r=0..3).
// Gate-exp2 hoisted into the MFMA region (2 gate-groups) so trans issue/latency
// overlaps matrix-pipe time; values bit-identical to sigmoid_f/tanh_f path.
__global__ __launch_bounds__(512, 2) void enc_kernel(
    const float* __restrict__ Xc, const void* __restrict__ Wraw,
    const float* __restrict__ P, float* __restrict__ Cout)
{
    const int n = blockIdx.y, b0 = blockIdx.x * BT;
    const int tid = threadIdx.x;
    const int w = tid >> 6, lane = tid & 63;
    const int l15 = lane & 15, quad = lane >> 4;
    const int wbf = P[OFF_FLAGS + 1] > 0.5f;
    const int bown = b0 + l15;

    __shared__ alignas(16) ushort_t hS[2][16 * 136];
    for (int i = tid; i < 16 * 136; i += 512) hS[0][i] = 0;

    // A-fragments (weights): lane holds W[g = typ*128 + 16w + l15][k = 32kc+8quad+j]
    bf16x8 afrag[4][4];
    #pragma unroll
    for (int typ = 0; typ < 4; typ++) {
        const int g = typ * 128 + 16 * w + l15;
        #pragma unroll
        for (int kc = 0; kc < 4; kc++) {
            const int base = (n * G4 + g) * DD + 32 * kc + 8 * quad;
            if (wbf) {
                afrag[typ][kc] = *(const bf16x8*)((const ushort_t*)Wraw + base);
            } else {
                const float* fp = (const float*)Wraw + base;
                afrag[typ][kc] = pack8(*(const f32x4*)fp, *(const f32x4*)(fp + 4));
            }
        }
    }

    // pool A-fragment: rows 0 and 8 carry pw (so both 32-lane halves get s)
    bf16x8 pfrag[4];
    #pragma unroll
    for (int kc = 0; kc < 4; kc++) {
        bf16x8 tmp;
        #pragma unroll
        for (int j = 0; j < 8; j++)
            tmp[j] = (l15 == 0 || l15 == 8)
                   ? (short)f2bf(P[OFF_PW + n * DD + 32 * kc + 8 * quad + j]) : (short)0;
        pfrag[kc] = tmp;
    }

    f32x4 bias4[4], wih4[4];
    #pragma unroll
    for (int typ = 0; typ < 4; typ++) {
        int base = n * G4 + typ * 128 + 16 * w + 4 * quad;
        bias4[typ] = *(const f32x4*)&P[OFF_EB + base];
        wih4[typ]  = *(const f32x4*)&P[OFF_WIH + base];
    }
    const float pb_r = P[OFF_PB + n];
    const f32x4 pb4 = {pb_r, pb_r, pb_r, pb_r};

    float cst[4] = {0.f, 0.f, 0.f, 0.f};
    f32x4 hpair[2];
    hpair[0] = f32x4{0.f, 0.f, 0.f, 0.f};
    hpair[1] = f32x4{0.f, 0.f, 0.f, 0.f};
    f32x4 Cacc   = {0.f, 0.f, 0.f, 0.f};
    float lR = 0.f, pend = 0.f;

    const float* xnext = Xc + n * 128 + bown;
    float xq = *xnext;            // t = 0
    xnext += 4096;

    // static priority asymmetry: per SIMD one hi-prio and one lo-prio wave
    if (w & 4) __builtin_amdgcn_s_setprio(1);

#define ENC_STEP(T, RB)                                                              \
    do {                                                                             \
        LBAR();                                                                      \
        bf16x8 bh[4];                                                                \
        _Pragma("unroll")                                                            \
        for (int kc = 0; kc < 4; kc++)                                               \
            bh[kc] = *(const bf16x8*)&hS[RB][l15 * 136 + 32 * kc + 8 * quad];        \
        if ((T) >= 2) {   /* deferred pool update for h_{T-2} (in hpair[RB]) */      \
            float e = __expf(pend);                                                  \
            lR += e;                                                                 \
            f32x4 ev = {e, e, e, e};                                                 \
            Cacc += ev * hpair[RB];                                                  \
        }                                                                            \
        f32x4 xv = {xq, xq, xq, xq};                                                 \
        /* group 1: gates i,f — two independent MFMA chains, then their exp2s */     \
        f32x4 a0 = __builtin_amdgcn_mfma_f32_16x16x32_bf16(                          \
            afrag[0][0], bh[0], bias4[0] + xv * wih4[0], 0, 0, 0);                   \
        f32x4 a1 = __builtin_amdgcn_mfma_f32_16x16x32_bf16(                          \
            afrag[1][0], bh[0], bias4[1] + xv * wih4[1], 0, 0, 0);                   \
        _Pragma("unroll")                                                            \
        for (int kc = 1; kc < 4; kc++) {                                             \
            a0 = __builtin_amdgcn_mfma_f32_16x16x32_bf16(afrag[0][kc], bh[kc], a0, 0, 0, 0); \
            a1 = __builtin_amdgcn_mfma_f32_16x16x32_bf16(afrag[1][kc], bh[kc], a1, 0, 0, 0); \
        }                                                                            \
        float e_i[4], e_f[4];                                                        \
        _Pragma("unroll")                                                            \
        for (int r = 0; r < 4; r++) {                                                \
            e_i[r] = exp2_f(a0[r] * L1C);                                            \
            e_f[r] = exp2_f(a1[r] * L1C);                                            \
        }                                                                            \
        /* group 2: gates g,o + pool — their exp2s issue behind the chains */        \
        f32x4 a2 = __builtin_amdgcn_mfma_f32_16x16x32_bf16(                          \
            afrag[2][0], bh[0], bias4[2] + xv * wih4[2], 0, 0, 0);                   \
        f32x4 a3 = __builtin_amdgcn_mfma_f32_16x16x32_bf16(                          \
            afrag[3][0], bh[0], bias4[3] + xv * wih4[3], 0, 0, 0);                   \
        f32x4 aP = __builtin_amdgcn_mfma_f32_16x16x32_bf16(pfrag[0], bh[0], pb4, 0, 0, 0); \
        xq = *xnext; xnext += 4096;   /* over-read at T=126 stays inside Xc region */ \
        _Pragma("unroll")                                                            \
        for (int kc = 1; kc < 4; kc++) {                                             \
            a2 = __builtin_amdgcn_mfma_f32_16x16x32_bf16(afrag[2][kc], bh[kc], a2, 0, 0, 0); \
            a3 = __builtin_amdgcn_mfma_f32_16x16x32_bf16(afrag[3][kc], bh[kc], a3, 0, 0, 0); \
            aP = __builtin_amdgcn_mfma_f32_16x16x32_bf16(pfrag[kc], bh[kc], aP, 0, 0, 0); \
        }                                                                            \
        float e_g[4], e_o[4];                                                        \
        _Pragma("unroll")                                                            \
        for (int r = 0; r < 4; r++) {                                                \
            e_g[r] = exp2_f(a2[r] * L2C);                                            \
            e_o[r] = exp2_f(a3[r] * L1C);                                            \
        }                                                                            \
        if ((T) >= 1) pend = swz_bcast_l15(aP[0]);  /* score of h_{T-1} */           \
        float hh[4];                                                                 \
        _Pragma("unroll")                                                            \
        for (int r = 0; r < 4; r++) {                                                \
            float ii = __builtin_amdgcn_rcpf(1.f + e_i[r]);                          \
            float ff = __builtin_amdgcn_rcpf(1.f + e_f[r]);                          \
            float g2 = 1.f - 2.f * __builtin_amdgcn_rcpf(e_g[r] + 1.f);              \
            float oo = __builtin_amdgcn_rcpf(1.f + e_o[r]);                          \
            float cc = ff * cst[r] + ii * g2;                                        \
            cst[r] = cc;                                                             \
            hh[r] = oo * tanh_f(cc);                                                 \
        }                                                                            \
        hpair[RB].x = hh[0]; hpair[RB].y = hh[1];                                    \
        hpair[RB].z = hh[2]; hpair[RB].w = hh[3];                                    \
        uint2 hw;                                                                    \
        hw.x = cvt_pk_bf16(hh[0], hh[1]);                                            \
        hw.y = cvt_pk_bf16(hh[2], hh[3]);                                            \
        *(uint2*)&hS[(RB) ^ 1][l15 * 136 + 16 * w + 4 * quad] = hw;                  \
    } while (0)

    for (int tp = 0; tp < 63; tp++) {
        ENC_STEP(2 * tp, 0);
        ENC_STEP(2 * tp + 1, 1);
    }
    ENC_STEP(126, 0);
#undef ENC_STEP

    // final fold: consume pend(126)=score(h_125) with hpair[1]; then fresh score of
    // h_126 (in hS[1] / hpair[0]).
    LBAR();
    {
        float e = __expf(pend);
        lR += e;
        f32x4 ev = {e, e, e, e};
        Cacc += ev * hpair[1];

        f32x4 accP = __builtin_amdgcn_mfma_f32_16x16x32_bf16(
            pfrag[0], *(const bf16x8*)&hS[1][l15 * 136 + 8 * quad], pb4, 0, 0, 0);
        #pragma unroll
        for (int kc = 1; kc < 4; kc++) {
            bf16x8 bh = *(const bf16x8*)&hS[1][l15 * 136 + 32 * kc + 8 * quad];
            accP = __builtin_amdgcn_mfma_f32_16x16x32_bf16(pfrag[kc], bh, accP, 0, 0, 0);
        }
        float e2 = __expf(swz_bcast_l15(accP[0]));
        lR += e2;
        f32x4 ev2 = {e2, e2, e2, e2};
        Cacc += ev2 * hpair[0];
    }
    float inv = 1.f / lR;
    f32x4 iv = {inv, inv, inv, inv};
    f32x4 cv = Cacc * iv;
    *(f32x4*)&Cout[bown * (NV * DD) + n * DD + 16 * w + 4 * quad] = cv;
}

// ---------------- QKV projection ----------------
__global__ __launch_bounds__(256) void qkv_kernel(
    const float* __restrict__ C, const float* __restrict__ P,
    float* __restrict__ q, float* __restrict__ k, float* __restrict__ v)
{
    int b = blockIdx.x, p = blockIdx.y, tid = threadIdx.x;
    int j = tid & 127, half = tid >> 7;
    __shared__ float Cb[NV * DD];
    for (int i = tid; i < NV * DD; i += 256) Cb[i] = C[b * (NV * DD) + i];
    __syncthreads();

    const float* wrow = P + OFF_INW + (p * DD + j) * DD;
    float bias = P[OFF_INB + p * DD + j];
    float acc[16];
    #pragma unroll
    for (int nn = 0; nn < 16; nn++) acc[nn] = bias;

    for (int dc = 0; dc < DD; dc += 8) {
        float4 w0 = *(const float4*)&wrow[dc];
        float4 w1 = *(const float4*)&wrow[dc + 4];
        #pragma unroll
        for (int nn = 0; nn < 16; nn++) {
            const float* cb = &Cb[(half * 16 + nn) * DD + dc];
            float4 c0 = *(float4*)&cb[0];
            float4 c1 = *(float4*)&cb[4];
            acc[nn] += c0.x * w0.x + c0.y * w0.y + c0.z * w0.z + c0.w * w0.w
                     + c1.x * w1.x + c1.y * w1.y + c1.z * w1.z + c1.w * w1.w;
        }
    }
    float* dst = (p == 0) ? q : (p == 1) ? k : v;
    for (int nn = 0; nn < 16; nn++)
        dst[b * (NV * DD) + (half * 16 + nn) * DD + j] = acc[nn];
}

// ---------------- cross-attention + out-proj + residual, split by query-half ----------------
// 256 threads: thread = (hh = tid>>5, sub = (tid>>4)&1, qi = tid&15); each sub owns
// 16 of the 32 keys; max/denominator/Oacc combined via shfl_xor(.,16) (intra-wave:
// each hh's 32 threads sit in one wave). Doubles waves/CU, halves per-thread FLOPs.
__global__ __launch_bounds__(256) void attn_kernel(
    const float* __restrict__ q, const float* __restrict__ k, const float* __restrict__ v,
    const float* __restrict__ C, const float* __restrict__ P,
    float* __restrict__ Cstar, void* __restrict__ dout)
{
    int b = blockIdx.x, half = blockIdx.y, tid = threadIdx.x;
    int obf = P[OFF_FLAGS + 0] > 0.5f;
    int n0 = half * 16;
    __shared__ float Qs[16 * DD], Ks[NV * DD], Vs[NV * DD];
    float* Os = Ks;   // reused after last Ks read (sync-separated)
    for (int i = tid; i < 16 * DD; i += 256) Qs[i] = q[b * (NV * DD) + n0 * DD + i];
    __syncthreads();

    int qi = tid & 15, sub = (tid >> 4) & 1, hh = tid >> 5;   // 8 heads x 2 subs x 16 queries
    int kk0 = sub * 16;
    float qreg[16];
    #pragma unroll
    for (int u = 0; u < 4; u++) {
        float4 t4 = *(float4*)&Qs[qi * DD + hh * 16 + 4 * u];
        qreg[4*u] = t4.x; qreg[4*u+1] = t4.y; qreg[4*u+2] = t4.z; qreg[4*u+3] = t4.w;
    }

    float Oacc[16];
    #pragma unroll
    for (int u = 0; u < 16; u++) Oacc[u] = 0.f;
    float wsum = 0.f;
    int tmax = (b < 5) ? b : 5;

    // reg prefetch buffers: 4 float4 each (1024 float4 per array / 256 threads)
    float4 kr[4], vr[4];
#define ATT_LOAD(TAU)                                                            \
    do {                                                                         \
        const float4* kp = (const float4*)&k[(b - (TAU)) * (NV * DD)];           \
        const float4* vp = (const float4*)&v[(b - (TAU)) * (NV * DD)];           \
        _Pragma("unroll")                                                        \
        for (int u = 0; u < 4; u++) {                                            \
            kr[u] = kp[tid + 256 * u];                                           \
            vr[u] = vp[tid + 256 * u];                                           \
        }                                                                        \
    } while (0)

    if (tmax >= 1) ATT_LOAD(1);

    for (int tau = 1; tau <= tmax; tau++) {
        __syncthreads();
        #pragma unroll
        for (int u = 0; u < 4; u++) {
            ((float4*)Ks)[tid + 256 * u] = kr[u];
            ((float4*)Vs)[tid + 256 * u] = vr[u];
        }
        __syncthreads();
        if (tau < tmax) ATT_LOAD(tau + 1);   // issue next-tau loads; hide under compute

        float s[16];
        #pragma unroll
        for (int kk = 0; kk < 16; kk++) {
            float a = 0.f;
            #pragma unroll
            for (int u = 0; u < 4; u++) {
                float4 kv = *(float4*)&Ks[(kk0 + kk) * DD + hh * 16 + 4 * u];
                a += qreg[4*u] * kv.x + qreg[4*u+1] * kv.y
                   + qreg[4*u+2] * kv.z + qreg[4*u+3] * kv.w;
            }
            s[kk] = a * 0.25f;
        }
        float mm = s[0];
        #pragma unroll
        for (int kk = 1; kk < 16; kk++) mm = fmaxf(mm, s[kk]);
        mm = fmaxf(mm, __shfl_xor(mm, 16));          // full 32-key max
        float ssum = 0.f;
        #pragma unroll
        for (int kk = 0; kk < 16; kk++) { s[kk] = __expf(s[kk] - mm); ssum += s[kk]; }
        ssum += __shfl_xor(ssum, 16);                // full 32-key denom
        float wdk = __expf(-0.7f * (float)(tau - 1));
        wsum += wdk;
        float wr = wdk / ssum;
        #pragma unroll
        for (int u = 0; u < 4; u++) {
            float ax = 0.f, ay = 0.f, az = 0.f, aw = 0.f;
            #pragma unroll
            for (int kk = 0; kk < 16; kk++) {
                float4 vv = *(float4*)&Vs[(kk0 + kk) * DD + hh * 16 + 4 * u];
                ax += s[kk] * vv.x; ay += s[kk] * vv.y;
                az += s[kk] * vv.z; aw += s[kk] * vv.w;
            }
            Oacc[4*u] += wr * ax; Oacc[4*u+1] += wr * ay;
            Oacc[4*u+2] += wr * az; Oacc[4*u+3] += wr * aw;
        }
    }
#undef ATT_LOAD

    // combine the two key-halves
    #pragma unroll
    for (int u = 0; u < 16; u++) Oacc[u] += __shfl_xor(Oacc[u], 16);

    __syncthreads();
    float winv = (b > 0) ? 1.f / wsum : 0.f;
    if (sub == 0) {
        #pragma unroll
        for (int u = 0; u < 16; u++)
            Os[qi * DD + hh * 16 + u] = Oacc[u] * winv;   // Os rows = local queries 0..15
    }
    __syncthreads();

    int j = tid & 127;            // output column
    int half2 = tid >> 7;         // row-halves 0/1 -> nn 0..7 / 8..15
    const float* wrow = P + OFF_OUTW + j * DD;
    float obias = P[OFF_OUTB + j];
    for (int nn = half2 * 8; nn < half2 * 8 + 8; nn++) {
        float a = (b > 0) ? obias : 0.f;
        for (int dc = 0; dc < DD; dc += 8) {
            float4 w0 = *(const float4*)&wrow[dc];
            float4 w1 = *(const float4*)&wrow[dc + 4];
            float4 o0 = *(float4*)&Os[nn * DD + dc];
            float4 o1 = *(float4*)&Os[nn * DD + dc + 4];
            a += o0.x*w0.x + o0.y*w0.y + o0.z*w0.z + o0.w*w0.w
               + o1.x*w1.x + o1.y*w1.y + o1.z*w1.z + o1.w*w1.w;
        }
        int nng = n0 + nn;
        float cs = C[b * (NV * DD) + nng * DD + j] + a;
        Cstar[b * (NV * DD) + nng * DD + j] = cs;
        store_out(dout, 524288 + b * (NV * DD) + nng * DD + j, cs, obf);
    }
}

// ===================== decoder: fused init + operand-swapped MFMA recurrence =====================
__global__ __launch_bounds__(512, 2) void dec_kernel(
    const float* __restrict__ Cstar,
    const void* __restrict__ iHw, const void* __restrict__ iCw,
    const void* __restrict__ Wraw,
    const float* __restrict__ P, void* __restrict__ out)
{
    const int n = blockIdx.y, b0 = blockIdx.x * BT;
    const int tid = threadIdx.x;
    const int w = tid >> 6, lane = tid & 63;
    const int l15 = lane & 15, quad = lane >> 4;
    const int obf = P[OFF_FLAGS + 0] > 0.5f;
    const int hbf = P[OFF_FLAGS + 2] > 0.5f;
    const int cbf = P[OFF_FLAGS + 3] > 0.5f;
    const int wbf = P[OFF_FLAGS + 4] > 0.5f;
    const int bown = b0 + l15;

    __shared__ alignas(16) ushort_t hS[2][16 * 136];

    // ---- fused init: D[e-row][b-col] = Cst.W^T + b ----
    bf16x8 cstB[4];
    #pragma unroll
    for (int kc = 0; kc < 4; kc++) {
        const float* cp = &Cstar[bown * (NV * DD) + n * DD + 32 * kc + 8 * quad];
        cstB[kc] = pack8(*(const f32x4*)&cp[0], *(const f32x4*)&cp[4]);
    }
    float cst[4];
    {
        f32x4 hAcc = *(const f32x4*)&P[OFF_IHB + n * DD + 16 * w + 4 * quad];
        f32x4 cAcc = *(const f32x4*)&P[OFF_ICB + n * DD + 16 * w + 4 * quad];
        #pragma unroll
        for (int kc = 0; kc < 4; kc++) {
            const int base = (n * DD + 16 * w + l15) * DD + 32 * kc + 8 * quad;
            bf16x8 wA;
            if (hbf) wA = *(const bf16x8*)((const ushort_t*)iHw + base);
            else {
                const float* fp = (const float*)iHw + base;
                wA = pack8(*(const f32x4*)fp, *(const f32x4*)(fp + 4));
            }
            hAcc = __builtin_amdgcn_mfma_f32_16x16x32_bf16(wA, cstB[kc], hAcc, 0, 0, 0);
            if (cbf) wA = *(const bf16x8*)((const ushort_t*)iCw + base);
            else {
                const float* fp = (const float*)iCw + base;
                wA = pack8(*(const f32x4*)fp, *(const f32x4*)(fp + 4));
            }
            cAcc = __builtin_amdgcn_mfma_f32_16x16x32_bf16(wA, cstB[kc], cAcc, 0, 0, 0);
        }
        float h0 = tanh_f(hAcc[0]), h1 = tanh_f(hAcc[1]);
        float h2 = tanh_f(hAcc[2]), h3 = tanh_f(hAcc[3]);
        #pragma unroll
        for (int r = 0; r < 4; r++) cst[r] = tanh_f(cAcc[r]);
        uint2 hw;
        hw.x = cvt_pk_bf16(h0, h1);
        hw.y = cvt_pk_bf16(h2, h3);
        *(uint2*)&hS[0][l15 * 136 + 16 * w + 4 * quad] = hw;
    }

    // ---- recurrence weights (A-operand) ----
    bf16x8 afrag[4][4];
    #pragma unroll
    for (int typ = 0; typ < 4; typ++) {
        const int g = typ * 128 + 16 * w + l15;
        #pragma unroll
        for (int kc = 0; kc < 4; kc++) {
            const int base = (n * G4 + g) * DD + 32 * kc + 8 * quad;
            if (wbf) {
                afrag[typ][kc] = *(const bf16x8*)((const ushort_t*)Wraw + base);
            } else {
                const float* fp = (const float*)Wraw + base;
                afrag[typ][kc] = pack8(*(const f32x4*)fp, *(const f32x4*)(fp + 4));
            }
        }
    }

    // out-proj A-fragment: row 0 = ow (every wave holds it; out-proj rotates per step)
    bf16x8 pfrag[4];
    #pragma unroll
    for (int kc = 0; kc < 4; kc++) {
        bf16x8 tmp;
        #pragma unroll
        for (int j = 0; j < 8; j++)
            tmp[j] = (l15 == 0) ? (short)f2bf(P[OFF_DOW + n * DD + 32 * kc + 8 * quad + j]) : (short)0;
        pfrag[kc] = tmp;
    }

    f32x4 bias4[4];
    #pragma unroll
    for (int typ = 0; typ < 4; typ++) {
        int base = n * G4 + typ * 128 + 16 * w + 4 * quad;
        f32x4 b1 = *(const f32x4*)&P[OFF_DBIH + base];
        f32x4 b2 = *(const f32x4*)&P[OFF_DBHH + base];
        bias4[typ] = b1 + b2;
    }
    const float ob_r = P[OFF_DOB + n];
    const f32x4 ob4 = {ob_r, ob_r, ob_r, ob_r};

    // static priority asymmetry: per SIMD one hi-prio and one lo-prio wave
    if (w & 4) __builtin_amdgcn_s_setprio(1);

#define DEC_STEP(T, RB)                                                              \
    do {                                                                             \
        LBAR();                                                                      \
        bf16x8 bh[4];                                                                \
        _Pragma("unroll")                                                            \
        for (int kc = 0; kc < 4; kc++)                                               \
            bh[kc] = *(const bf16x8*)&hS[RB][l15 * 136 + 32 * kc + 8 * quad];        \
        /* group 1: gates i,f */                                                     \
        f32x4 a0 = __builtin_amdgcn_mfma_f32_16x16x32_bf16(afrag[0][0], bh[0], bias4[0], 0, 0, 0); \
        f32x4 a1 = __builtin_amdgcn_mfma_f32_16x16x32_bf16(afrag[1][0], bh[0], bias4[1], 0, 0, 0); \
        _Pragma("unroll")                                                            \
        for (int kc = 1; kc < 4; kc++) {                                             \
            a0 = __builtin_amdgcn_mfma_f32_16x16x32_bf16(afrag[0][kc], bh[kc], a0, 0, 0, 0); \
            a1 = __builtin_amdgcn_mfma_f32_16x16x32_bf16(afrag[1][kc], bh[kc], a1, 0, 0, 0); \
        }                                                                            \
        float e_i[4], e_f[4];                                                        \
        _Pragma("unroll")                                                            \
        for (int r = 0; r < 4; r++) {                                                \
            e_i[r] = exp2_f(a0[r] * L1C);                                            \
            e_f[r] = exp2_f(a1[r] * L1C);                                            \
        }                                                                            \
        /* group 2: gates g,o (+ rotating out-proj) */                               \
        f32x4 a2 = __builtin_amdgcn_mfma_f32_16x16x32_bf16(afrag[2][0], bh[0], bias4[2], 0, 0, 0); \
        f32x4 a3 = __builtin_amdgcn_mfma_f32_16x16x32_bf16(afrag[3][0], bh[0], bias4[3], 0, 0, 0); \
        _Pragma("unroll")                                                            \
        for (int kc = 1; kc < 4; kc++) {                                             \
            a2 = __builtin_amdgcn_mfma_f32_16x16x32_bf16(afrag[2][kc], bh[kc], a2, 0, 0, 0); \
            a3 = __builtin_amdgcn_mfma_f32_16x16x32_bf16(afrag[3][kc], bh[kc], a3, 0, 0, 0); \
        }                                                                            \
        if (w == ((T) & 7)) {   /* rotate out-proj wave to balance the extra work */ \
            f32x4 accP = __builtin_amdgcn_mfma_f32_16x16x32_bf16(pfrag[0], bh[0], ob4, 0, 0, 0); \
            _Pragma("unroll")                                                        \
            for (int kc = 1; kc < 4; kc++)                                           \
                accP = __builtin_amdgcn_mfma_f32_16x16x32_bf16(pfrag[kc], bh[kc], accP, 0, 0, 0); \
            if ((T) > 0 && quad == 0)                                                \
                store_out(out, (long)bown * 4064 + (long)((T) - 1) * NV + n, accP[0], obf); \
        }                                                                            \
        float e_g[4], e_o[4];                                                        \
        _Pragma("unroll")                                                            \
        for (int r = 0; r < 4; r++) {                                                \
            e_g[r] = exp2_f(a2[r] * L2C);                                            \
            e_o[r] = exp2_f(a3[r] * L1C);                                            \
        }                                                                            \
        float hh[4];                                                                 \
        _Pragma("unroll")                                                            \
        for (int r = 0; r < 4; r++) {                                                \
            float ii = __builtin_amdgcn_rcpf(1.f + e_i[r]);                          \
            float ff = __builtin_amdgcn_rcpf(1.f + e_f[r]);                          \
            float g2 = 1.f - 2.f * __builtin_amdgcn_rcpf(e_g[r] + 1.f);              \
            float oo = __builtin_amdgcn_rcpf(1.f + e_o[r]);                          \
            float cc = ff * cst[r] + ii * g2;                                        \
            cst[r] = cc;                                                             \
            hh[r] = oo * tanh_f(cc);                                                 \
        }                                                                            \
        uint2 hw;                                                                    \
        hw.x = cvt_pk_bf16(hh[0], hh[1]);                                            \
        hw.y = cvt_pk_bf16(hh[2], hh[3]);                                            \
        *(uint2*)&hS[(RB) ^ 1][l15 * 136 + 16 * w + 4 * quad] = hw;                  \
    } while (0)

    for (int tp = 0; tp < 64; tp++) {
        DEC_STEP(2 * tp, 0);
        DEC_STEP(2 * tp + 1, 1);
    }
#undef DEC_STEP

    // o_127 from h_127 (t=127 wrote hS[0]); 128 & 7 == 0 -> wave 0, consistent with rotation
    LBAR();
    if (w == 0) {
        f32x4 accP = __builtin_amdgcn_mfma_f32_16x16x32_bf16(
            pfrag[0], *(const bf16x8*)&hS[0][l15 * 136 + 8 * quad], ob4, 0, 0, 0);
        #pragma unroll
        for (int kc = 1; kc < 4; kc++) {
            bf16x8 bh = *(const bf16x8*)&hS[0][l15 * 136 + 32 * kc + 8 * quad];
            accP = __builtin_amdgcn_mfma_f32_16x16x32_bf16(pfrag[kc], bh, accP, 0, 0, 0);
        }
        if (quad == 0)
            store_out(out, 520192 + (long)bown * NV + n, accP[0], obf);
    }
}

extern "C" void kernel_launch(void* const* d_in, const int* in_sizes, int n_in,
                              void* d_out, int out_size, void* d_ws, size_t ws_size,
                              hipStream_t stream) {
    char* ws = (char*)d_ws;
    float*    P    = (float*)(ws + 0);              // ~595 KB
    float*    Xc   = (float*)(ws + (1u << 20));     // 2 MB
    float*    C    = (float*)(ws + (3u << 20));     // 2 MB
    float*    qb   = (float*)(ws + (5u << 20));
    float*    kb   = (float*)(ws + (7u << 20));
    float*    vb   = (float*)(ws + (9u << 20));
    float*    Cst  = (float*)(ws + (11u << 20));

    Ptr19 a;
    for (int i = 0; i < 19; i++) a.p[i] = d_in[i];

    prep_kernel<<<842, 256, 0, stream>>>(a, P, Xc);
    enc_kernel<<<dim3(8, 32), 512, 0, stream>>>(Xc, d_in[2], P, C);
    qkv_kernel<<<dim3(128, 3), 256, 0, stream>>>(C, P, qb, kb, vb);
    attn_kernel<<<dim3(128, 2), 256, 0, stream>>>(qb, kb, vb, C, P, Cst, d_out);
    dec_kernel<<<dim3(8, 32), 512, 0, stream>>>(Cst, d_in[10], d_in[12], d_in[14], P, d_out);
}

// Round 9
// 410.831 us; speedup vs baseline: 1.0204x; 1.0047x over previous
//
#include <hip/hip_runtime.h>
#include <hip/hip_bf16.h>

typedef unsigned short ushort_t;
typedef unsigned int uint_t;

#define DD   128
#define G4   512
#define BT   16
#define NB   128
#define NV   32

// param block offsets (floats), each section 256-aligned so prep blocks map 1:1 to sources
#define OFF_WIH   0
#define OFF_EB    16384
#define OFF_PW    32768
#define OFF_PB    36864
#define OFF_INW   37120
#define OFF_INB   86272
#define OFF_OUTW  86784
#define OFF_OUTB  103168
#define OFF_IHB   103424
#define OFF_ICB   107520
#define OFF_DBIH  111616
#define OFF_DBHH  128000
#define OFF_DOW   144384
#define OFF_DOB   148480
#define P_TOTAL   148736   // = 581 * 256
// dtype flags stashed in PB-section padding: [32]=X, [33]=eWhh, [34]=iHw, [35]=iCw, [36]=dWhh
#define OFF_FLAGS (OFF_PB + 32)

typedef __attribute__((ext_vector_type(8))) short bf16x8;
typedef __attribute__((ext_vector_type(4))) float f32x4;

__device__ __forceinline__ float bf2f(ushort_t u) {
    union { uint_t i; float f; } x; x.i = ((uint_t)u) << 16; return x.f;
}
__device__ __forceinline__ ushort_t f2bf(float f) {
    __hip_bfloat16 h = __float2bfloat16(f);   // RNE
    return *(ushort_t*)&h;
}
__device__ __forceinline__ uint_t f2u(float f) {
    union { float f; uint_t i; } x; x.f = f; return x.i;
}
__device__ __forceinline__ float u2f(uint_t u) {
    union { uint_t i; float f; } x; x.i = u; return x.f;
}
// raw v_exp_f32 (2^x)
__device__ __forceinline__ float exp2_f(float x) {
    float r; asm("v_exp_f32 %0, %1" : "=v"(r) : "v"(x)); return r;
}
#define L1C (-1.442695041f)
#define L2C (2.885390082f)
// sigmoid(x) = rcp(1 + 2^(-x*log2e))  -- saturates gracefully at both ends
__device__ __forceinline__ float sigmoid_f(float x) {
    return __builtin_amdgcn_rcpf(1.f + exp2_f(x * L1C));
}
// tanh(x) = 1 - 2*rcp(2^(2x*log2e)+1) -- saturates gracefully (rcp(inf)=0 -> 1)
__device__ __forceinline__ float tanh_f(float x) {
    return 1.f - 2.f * __builtin_amdgcn_rcpf(exp2_f(x * L2C) + 1.f);
}
// packed f32 -> 2x bf16 (RNE), guaranteed 1 instr
__device__ __forceinline__ uint_t cvt_pk_bf16(float a, float b) {
    uint_t r; asm("v_cvt_pk_bf16_f32 %0, %1, %2" : "=v"(r) : "v"(a), "v"(b)); return r;
}
__device__ __forceinline__ bf16x8 pack8(f32x4 a, f32x4 b) {
    union { uint_t u[4]; bf16x8 v; } x;
    x.u[0] = cvt_pk_bf16(a.x, a.y); x.u[1] = cvt_pk_bf16(a.z, a.w);
    x.u[2] = cvt_pk_bf16(b.x, b.y); x.u[3] = cvt_pk_bf16(b.z, b.w);
    return x.v;
}
__device__ __forceinline__ float swz_bcast_l15(float v) {
    // BitMode and=0x0F: new_lane = lane & 15 (within each 32-lane half)
    return u2f((uint_t)__builtin_amdgcn_ds_swizzle((int)f2u(v), 0x000F));
}
__device__ __forceinline__ void store_out(void* out, long idx, float v, int bf) {
    if (bf) ((ushort_t*)out)[idx] = f2bf(v);
    else    ((float*)out)[idx]    = v;
}
// light barrier: drain LDS only; global loads/stores stay in flight across it.
#define LBAR() do { asm volatile("s_waitcnt lgkmcnt(0)" ::: "memory"); \
                    __builtin_amdgcn_s_barrier(); } while (0)

// per-wave dtype probe: 1 if data looks bf16 when read as ushort
__device__ __forceinline__ int wave_probe(const void* p, int elems) {
    int cap = elems < 1024 ? elems : 1024;
    int lane = threadIdx.x & 63;
    const ushort_t* u = (const ushort_t*)p;
    int cnt = 0, tot = 0;
    for (int j = lane; j < cap; j += 64) {
        ushort_t x = u[j];
        float af = fabsf(bf2f(x));
        tot++;
        if (x == 0 || (af > 1e-7f && af < 100.f)) cnt++;
    }
    #pragma unroll
    for (int off = 32; off >= 1; off >>= 1) {
        cnt += __shfl_xor(cnt, off);
        tot += __shfl_xor(tot, off);
    }
    return (cnt * 10 >= tot * 9) ? 1 : 0;
}

struct Ptr19 { const void* p[19]; };

// ---------------- prep: params (581) + X transpose (256) + dtype flags (5) ----------------
__global__ __launch_bounds__(256) void prep_kernel(Ptr19 a, float* __restrict__ P,
                                                   float* __restrict__ Xc) {
    __shared__ float tile[32][65];
    if (blockIdx.x < 581) {
        int base = blockIdx.x * 256;
        int src, o0, size;
        if      (base < OFF_EB)   { src = 1;  o0 = base - OFF_WIH;  size = 16384; }
        else if (base < OFF_PW)   { src = 3;  o0 = base - OFF_EB;   size = 16384; }
        else if (base < OFF_PB)   { src = 4;  o0 = base - OFF_PW;   size = 4096;  }
        else if (base < OFF_INW)  { src = 5;  o0 = base - OFF_PB;   size = 32;    }
        else if (base < OFF_INB)  { src = 6;  o0 = base - OFF_INW;  size = 49152; }
        else if (base < OFF_OUTW) { src = 7;  o0 = base - OFF_INB;  size = 384;   }
        else if (base < OFF_OUTB) { src = 8;  o0 = base - OFF_OUTW; size = 16384; }
        else if (base < OFF_IHB)  { src = 9;  o0 = base - OFF_OUTB; size = 128;   }
        else if (base < OFF_ICB)  { src = 11; o0 = base - OFF_IHB;  size = 4096;  }
        else if (base < OFF_DBIH) { src = 13; o0 = base - OFF_ICB;  size = 4096;  }
        else if (base < OFF_DBHH) { src = 15; o0 = base - OFF_DBIH; size = 16384; }
        else if (base < OFF_DOW)  { src = 16; o0 = base - OFF_DBHH; size = 16384; }
        else if (base < OFF_DOB)  { src = 17; o0 = base - OFF_DOW;  size = 4096;  }
        else                      { src = 18; o0 = base - OFF_DOB;  size = 32;    }
        int bf = wave_probe(a.p[src], size);
        int off = o0 + (int)threadIdx.x;
        if (off < size)
            P[base + threadIdx.x] = bf ? bf2f(((const ushort_t*)a.p[src])[off])
                                       : ((const float*)a.p[src])[off];
    } else if (blockIdx.x < 837) {
        int bf = wave_probe(a.p[0], 1024);
        int idx2 = blockIdx.x - 581;
        int bt = (idx2 & 3) * 32, tn0 = (idx2 >> 2) * 64;
        const void* src = a.p[0];
        int tx = threadIdx.x & 63, ty = threadIdx.x >> 6;
        #pragma unroll
        for (int k = 0; k < 8; k++) {
            int row = ty * 8 + k;
            int idx = (bt + row) * 4096 + tn0 + tx;
            tile[row][tx] = bf ? bf2f(((const ushort_t*)src)[idx]) : ((const float*)src)[idx];
        }
        __syncthreads();
        int bx = threadIdx.x & 31, tyy = threadIdx.x >> 5;
        #pragma unroll
        for (int k = 0; k < 8; k++) {
            int tn = tn0 + tyy * 8 + k;
            int t = tn >> 5, nn = tn & 31;
            Xc[t * 4096 + nn * 128 + bt + bx] = tile[bx][tyy * 8 + k];
        }
    } else {
        int which = blockIdx.x - 837;            // 0..4
        int src = (which == 0) ? 0 : (which == 1) ? 2 : (which == 2) ? 10
                : (which == 3) ? 12 : 14;
        int flag = wave_probe(a.p[src], 1024);
        if (threadIdx.x == 0) P[OFF_FLAGS + which] = (float)flag;
    }
}

// ===================== encoder: operand-swapped MFMA recurrence =====================
// D[g-row][b-col]: thread owns (b = l15, d = 16w + 4quad + r, r=0..3).
// ANTI-PHASED schedules: even waves run the monolithic schedule (all MFMAs then all
// trans), odd waves run the split schedule (MFMA group / trans group alternating).
// Identical arithmetic + identical barrier count; stall windows of the two waves
// sharing a SIMD become complementary instead of aligned.
__global__ __launch_bounds__(512, 2) void enc_kernel(
    const float* __restrict__ Xc, const void* __restrict__ Wraw,
    const float* __restrict__ P, float* __restrict__ Cout)
{
    const int n = blockIdx.y, b0 = blockIdx.x * BT;
    const int tid = threadIdx.x;
    const int w = tid >> 6, lane = tid & 63;
    const int l15 = lane & 15, quad = lane >> 4;
    const int wbf = P[OFF_FLAGS + 1] > 0.5f;
    const int bown = b0 + l15;

    __shared__ alignas(16) ushort_t hS[2][16 * 136];
    for (int i = tid; i < 16 * 136; i += 512) hS[0][i] = 0;

    // A-fragments (weights): lane holds W[g = typ*128 + 16w + l15][k = 32kc+8quad+j]
    bf16x8 afrag[4][4];
    #pragma unroll
    for (int typ = 0; typ < 4; typ++) {
        const int g = typ * 128 + 16 * w + l15;
        #pragma unroll
        for (int kc = 0; kc < 4; kc++) {
            const int base = (n * G4 + g) * DD + 32 * kc + 8 * quad;
            if (wbf) {
                afrag[typ][kc] = *(const bf16x8*)((const ushort_t*)Wraw + base);
            } else {
                const float* fp = (const float*)Wraw + base;
                afrag[typ][kc] = pack8(*(const f32x4*)fp, *(const f32x4*)(fp + 4));
            }
        }
    }

    // pool A-fragment: rows 0 and 8 carry pw (so both 32-lane halves get s)
    bf16x8 pfrag[4];
    #pragma unroll
    for (int kc = 0; kc < 4; kc++) {
        bf16x8 tmp;
        #pragma unroll
        for (int j = 0; j < 8; j++)
            tmp[j] = (l15 == 0 || l15 == 8)
                   ? (short)f2bf(P[OFF_PW + n * DD + 32 * kc + 8 * quad + j]) : (short)0;
        pfrag[kc] = tmp;
    }

    f32x4 bias4[4], wih4[4];
    #pragma unroll
    for (int typ = 0; typ < 4; typ++) {
        int base = n * G4 + typ * 128 + 16 * w + 4 * quad;
        bias4[typ] = *(const f32x4*)&P[OFF_EB + base];
        wih4[typ]  = *(const f32x4*)&P[OFF_WIH + base];
    }
    const float pb_r = P[OFF_PB + n];
    const f32x4 pb4 = {pb_r, pb_r, pb_r, pb_r};

    float cst[4] = {0.f, 0.f, 0.f, 0.f};
    f32x4 hpair[2];
    hpair[0] = f32x4{0.f, 0.f, 0.f, 0.f};
    hpair[1] = f32x4{0.f, 0.f, 0.f, 0.f};
    f32x4 Cacc   = {0.f, 0.f, 0.f, 0.f};
    float lR = 0.f, pend = 0.f;

    const float* xnext = Xc + n * 128 + bown;
    float xq = *xnext;            // t = 0
    xnext += 4096;

    // static priority asymmetry: per SIMD one hi-prio and one lo-prio wave
    if (w & 4) __builtin_amdgcn_s_setprio(1);

// shared prologue: barrier, bh read, deferred pool update
#define ENC_HEAD(T, RB)                                                              \
        LBAR();                                                                      \
        bf16x8 bh[4];                                                                \
        _Pragma("unroll")                                                            \
        for (int kc = 0; kc < 4; kc++)                                               \
            bh[kc] = *(const bf16x8*)&hS[RB][l15 * 136 + 32 * kc + 8 * quad];        \
        if ((T) >= 2) {                                                              \
            float e = __expf(pend);                                                  \
            lR += e;                                                                 \
            f32x4 ev = {e, e, e, e};                                                 \
            Cacc += ev * hpair[RB];                                                  \
        }                                                                            \
        f32x4 xv = {xq, xq, xq, xq};

// shared epilogue: h store + history
#define ENC_TAIL(T, RB)                                                              \
        hpair[RB].x = hh[0]; hpair[RB].y = hh[1];                                    \
        hpair[RB].z = hh[2]; hpair[RB].w = hh[3];                                    \
        uint2 hw;                                                                    \
        hw.x = cvt_pk_bf16(hh[0], hh[1]);                                            \
        hw.y = cvt_pk_bf16(hh[2], hh[3]);                                            \
        *(uint2*)&hS[(RB) ^ 1][l15 * 136 + 16 * w + 4 * quad] = hw;

// variant A (even waves): monolithic — all 20 MFMAs, then the whole trans burst
#define ENC_STEP_A(T, RB)                                                            \
    do {                                                                             \
        ENC_HEAD(T, RB)                                                              \
        f32x4 acc[4];                                                                \
        _Pragma("unroll")                                                            \
        for (int typ = 0; typ < 4; typ++)                                            \
            acc[typ] = __builtin_amdgcn_mfma_f32_16x16x32_bf16(                      \
                afrag[typ][0], bh[0], bias4[typ] + xv * wih4[typ], 0, 0, 0);         \
        f32x4 aP = __builtin_amdgcn_mfma_f32_16x16x32_bf16(pfrag[0], bh[0], pb4, 0, 0, 0); \
        xq = *xnext; xnext += 4096;                                                  \
        _Pragma("unroll")                                                            \
        for (int kc = 1; kc < 4; kc++) {                                             \
            aP = __builtin_amdgcn_mfma_f32_16x16x32_bf16(pfrag[kc], bh[kc], aP, 0, 0, 0); \
            _Pragma("unroll")                                                        \
            for (int typ = 0; typ < 4; typ++)                                        \
                acc[typ] = __builtin_amdgcn_mfma_f32_16x16x32_bf16(afrag[typ][kc], bh[kc], acc[typ], 0, 0, 0); \
        }                                                                            \
        if ((T) >= 1) pend = swz_bcast_l15(aP[0]);                                   \
        float hh[4];                                                                 \
        _Pragma("unroll")                                                            \
        for (int r = 0; r < 4; r++) {                                                \
            float ii = sigmoid_f(acc[0][r]);                                         \
            float ff = sigmoid_f(acc[1][r]);                                         \
            float g2 = tanh_f(acc[2][r]);                                            \
            float oo = sigmoid_f(acc[3][r]);                                         \
            float cc = ff * cst[r] + ii * g2;                                        \
            cst[r] = cc;                                                             \
            hh[r] = oo * tanh_f(cc);                                                 \
        }                                                                            \
        ENC_TAIL(T, RB)                                                              \
    } while (0)

// variant B (odd waves): split — {i,f} MFMAs -> their exp2s -> {g,o,P} MFMAs -> theirs
#define ENC_STEP_B(T, RB)                                                            \
    do {                                                                             \
        ENC_HEAD(T, RB)                                                              \
        f32x4 a0 = __builtin_amdgcn_mfma_f32_16x16x32_bf16(                          \
            afrag[0][0], bh[0], bias4[0] + xv * wih4[0], 0, 0, 0);                   \
        f32x4 a1 = __builtin_amdgcn_mfma_f32_16x16x32_bf16(                          \
            afrag[1][0], bh[0], bias4[1] + xv * wih4[1], 0, 0, 0);                   \
        _Pragma("unroll")                                                            \
        for (int kc = 1; kc < 4; kc++) {                                             \
            a0 = __builtin_amdgcn_mfma_f32_16x16x32_bf16(afrag[0][kc], bh[kc], a0, 0, 0, 0); \
            a1 = __builtin_amdgcn_mfma_f32_16x16x32_bf16(afrag[1][kc], bh[kc], a1, 0, 0, 0); \
        }                                                                            \
        float e_i[4], e_f[4];                                                        \
        _Pragma("unroll")                                                            \
        for (int r = 0; r < 4; r++) {                                                \
            e_i[r] = exp2_f(a0[r] * L1C);                                            \
            e_f[r] = exp2_f(a1[r] * L1C);                                            \
        }                                                                            \
        f32x4 a2 = __builtin_amdgcn_mfma_f32_16x16x32_bf16(                          \
            afrag[2][0], bh[0], bias4[2] + xv * wih4[2], 0, 0, 0);                   \
        f32x4 a3 = __builtin_amdgcn_mfma_f32_16x16x32_bf16(                          \
            afrag[3][0], bh[0], bias4[3] + xv * wih4[3], 0, 0, 0);                   \
        f32x4 aP = __builtin_amdgcn_mfma_f32_16x16x32_bf16(pfrag[0], bh[0], pb4, 0, 0, 0); \
        xq = *xnext; xnext += 4096;                                                  \
        _Pragma("unroll")                                                            \
        for (int kc = 1; kc < 4; kc++) {                                             \
            a2 = __builtin_amdgcn_mfma_f32_16x16x32_bf16(afrag[2][kc], bh[kc], a2, 0, 0, 0); \
            a3 = __builtin_amdgcn_mfma_f32_16x16x32_bf16(afrag[3][kc], bh[kc], a3, 0, 0, 0); \
            aP = __builtin_amdgcn_mfma_f32_16x16x32_bf16(pfrag[kc], bh[kc], aP, 0, 0, 0); \
        }                                                                            \
        float e_g[4], e_o[4];                                                        \
        _Pragma("unroll")                                                            \
        for (int r = 0; r < 4; r++) {                                                \
            e_g[r] = exp2_f(a2[r] * L2C);                                            \
            e_o[r] = exp2_f(a3[r] * L1C);                                            \
        }                                                                            \
        if ((T) >= 1) pend = swz_bcast_l15(aP[0]);                                   \
        float hh[4];                                                                 \
        _Pragma("unroll")                                                            \
        for (int r = 0; r < 4; r++) {                                                \
            float ii = __builtin_amdgcn_rcpf(1.f + e_i[r]);                          \
            float ff = __builtin_amdgcn_rcpf(1.f + e_f[r]);                          \
            float g2 = 1.f - 2.f * __builtin_amdgcn_rcpf(e_g[r] + 1.f);              \
            float oo = __builtin_amdgcn_rcpf(1.f + e_o[r]);                          \
            float cc = ff * cst[r] + ii * g2;                                        \
            cst[r] = cc;                                                             \
            hh[r] = oo * tanh_f(cc);                                                 \
        }                                                                            \
        ENC_TAIL(T, RB)                                                              \
    } while (0)

    if (w & 1) {
        for (int tp = 0; tp < 63; tp++) {
            ENC_STEP_B(2 * tp, 0);
            ENC_STEP_B(2 * tp + 1, 1);
        }
        ENC_STEP_B(126, 0);
    } else {
        for (int tp = 0; tp < 63; tp++) {
            ENC_STEP_A(2 * tp, 0);
            ENC_STEP_A(2 * tp + 1, 1);
        }
        ENC_STEP_A(126, 0);
    }
#undef ENC_STEP_A
#undef ENC_STEP_B
#undef ENC_HEAD
#undef ENC_TAIL

    // final fold: consume pend(126)=score(h_125) with hpair[1]; then fresh score of
    // h_126 (in hS[1] / hpair[0]).
    LBAR();
    {
        float e = __expf(pend);
        lR += e;
        f32x4 ev = {e, e, e, e};
        Cacc += ev * hpair[1];

        f32x4 accP = __builtin_amdgcn_mfma_f32_16x16x32_bf16(
            pfrag[0], *(const bf16x8*)&hS[1][l15 * 136 + 8 * quad], pb4, 0, 0, 0);
        #pragma unroll
        for (int kc = 1; kc < 4; kc++) {
            bf16x8 bh = *(const bf16x8*)&hS[1][l15 * 136 + 32 * kc + 8 * quad];
            accP = __builtin_amdgcn_mfma_f32_16x16x32_bf16(pfrag[kc], bh, accP, 0, 0, 0);
        }
        float e2 = __expf(swz_bcast_l15(accP[0]));
        lR += e2;
        f32x4 ev2 = {e2, e2, e2, e2};
        Cacc += ev2 * hpair[0];
    }
    float inv = 1.f / lR;
    f32x4 iv = {inv, inv, inv, inv};
    f32x4 cv = Cacc * iv;
    *(f32x4*)&Cout[bown * (NV * DD) + n * DD + 16 * w + 4 * quad] = cv;
}

// ---------------- QKV projection ----------------
__global__ __launch_bounds__(256) void qkv_kernel(
    const float* __restrict__ C, const float* __restrict__ P,
    float* __restrict__ q, float* __restrict__ k, float* __restrict__ v)
{
    int b = blockIdx.x, p = blockIdx.y, tid = threadIdx.x;
    int j = tid & 127, half = tid >> 7;
    __shared__ float Cb[NV * DD];
    for (int i = tid; i < NV * DD; i += 256) Cb[i] = C[b * (NV * DD) + i];
    __syncthreads();

    const float* wrow = P + OFF_INW + (p * DD + j) * DD;
    float bias = P[OFF_INB + p * DD + j];
    float acc[16];
    #pragma unroll
    for (int nn = 0; nn < 16; nn++) acc[nn] = bias;

    for (int dc = 0; dc < DD; dc += 8) {
        float4 w0 = *(const float4*)&wrow[dc];
        float4 w1 = *(const float4*)&wrow[dc + 4];
        #pragma unroll
        for (int nn = 0; nn < 16; nn++) {
            const float* cb = &Cb[(half * 16 + nn) * DD + dc];
            float4 c0 = *(float4*)&cb[0];
            float4 c1 = *(float4*)&cb[4];
            acc[nn] += c0.x * w0.x + c0.y * w0.y + c0.z * w0.z + c0.w * w0.w
                     + c1.x * w1.x + c1.y * w1.y + c1.z * w1.z + c1.w * w1.w;
        }
    }
    float* dst = (p == 0) ? q : (p == 1) ? k : v;
    for (int nn = 0; nn < 16; nn++)
        dst[b * (NV * DD) + (half * 16 + nn) * DD + j] = acc[nn];
}

// ---------------- cross-attention + out-proj + residual, split by query-half ----------------
// 256 threads: thread = (hh = tid>>5, sub = (tid>>4)&1, qi = tid&15); each sub owns
// 16 of the 32 keys; max/denominator/Oacc combined via shfl_xor(.,16).
__global__ __launch_bounds__(256) void attn_kernel(
    const float* __restrict__ q, const float* __restrict__ k, const float* __restrict__ v,
    const float* __restrict__ C, const float* __restrict__ P,
    float* __restrict__ Cstar, void* __restrict__ dout)
{
    int b = blockIdx.x, half = blockIdx.y, tid = threadIdx.x;
    int obf = P[OFF_FLAGS + 0] > 0.5f;
    int n0 = half * 16;
    __shared__ float Qs[16 * DD], Ks[NV * DD], Vs[NV * DD];
    float* Os = Ks;   // reused after last Ks read (sync-separated)
    for (int i = tid; i < 16 * DD; i += 256) Qs[i] = q[b * (NV * DD) + n0 * DD + i];
    __syncthreads();

    int qi = tid & 15, sub = (tid >> 4) & 1, hh = tid >> 5;   // 8 heads x 2 subs x 16 queries
    int kk0 = sub * 16;
    float qreg[16];
    #pragma unroll
    for (int u = 0; u < 4; u++) {
        float4 t4 = *(float4*)&Qs[qi * DD + hh * 16 + 4 * u];
        qreg[4*u] = t4.x; qreg[4*u+1] = t4.y; qreg[4*u+2] = t4.z; qreg[4*u+3] = t4.w;
    }

    float Oacc[16];
    #pragma unroll
    for (int u = 0; u < 16; u++) Oacc[u] = 0.f;
    float wsum = 0.f;
    int tmax = (b < 5) ? b : 5;

    // reg prefetch buffers: 4 float4 each (1024 float4 per array / 256 threads)
    float4 kr[4], vr[4];
#define ATT_LOAD(TAU)                                                            \
    do {                                                                         \
        const float4* kp = (const float4*)&k[(b - (TAU)) * (NV * DD)];           \
        const float4* vp = (const float4*)&v[(b - (TAU)) * (NV * DD)];           \
        _Pragma("unroll")                                                        \
        for (int u = 0; u < 4; u++) {                                            \
            kr[u] = kp[tid + 256 * u];                                           \
            vr[u] = vp[tid + 256 * u];                                           \
        }                                                                        \
    } while (0)

    if (tmax >= 1) ATT_LOAD(1);

    for (int tau = 1; tau <= tmax; tau++) {
        __syncthreads();
        #pragma unroll
        for (int u = 0; u < 4; u++) {
            ((float4*)Ks)[tid + 256 * u] = kr[u];
            ((float4*)Vs)[tid + 256 * u] = vr[u];
        }
        __syncthreads();
        if (tau < tmax) ATT_LOAD(tau + 1);   // issue next-tau loads; hide under compute

        float s[16];
        #pragma unroll
        for (int kk = 0; kk < 16; kk++) {
            float a = 0.f;
            #pragma unroll
            for (int u = 0; u < 4; u++) {
                float4 kv = *(float4*)&Ks[(kk0 + kk) * DD + hh * 16 + 4 * u];
                a += qreg[4*u] * kv.x + qreg[4*u+1] * kv.y
                   + qreg[4*u+2] * kv.z + qreg[4*u+3] * kv.w;
            }
            s[kk] = a * 0.25f;
        }
        float mm = s[0];
        #pragma unroll
        for (int kk = 1; kk < 16; kk++) mm = fmaxf(mm, s[kk]);
        mm = fmaxf(mm, __shfl_xor(mm, 16));          // full 32-key max
        float ssum = 0.f;
        #pragma unroll
        for (int kk = 0; kk < 16; kk++) { s[kk] = __expf(s[kk] - mm); ssum += s[kk]; }
        ssum += __shfl_xor(ssum, 16);                // full 32-key denom
        float wdk = __expf(-0.7f * (float)(tau - 1));
        wsum += wdk;
        float wr = wdk / ssum;
        #pragma unroll
        for (int u = 0; u < 4; u++) {
            float ax = 0.f, ay = 0.f, az = 0.f, aw = 0.f;
            #pragma unroll
            for (int kk = 0; kk < 16; kk++) {
                float4 vv = *(float4*)&Vs[(kk0 + kk) * DD + hh * 16 + 4 * u];
                ax += s[kk] * vv.x; ay += s[kk] * vv.y;
                az += s[kk] * vv.z; aw += s[kk] * vv.w;
            }
            Oacc[4*u] += wr * ax; Oacc[4*u+1] += wr * ay;
            Oacc[4*u+2] += wr * az; Oacc[4*u+3] += wr * aw;
        }
    }
#undef ATT_LOAD

    // combine the two key-halves
    #pragma unroll
    for (int u = 0; u < 16; u++) Oacc[u] += __shfl_xor(Oacc[u], 16);

    __syncthreads();
    float winv = (b > 0) ? 1.f / wsum : 0.f;
    if (sub == 0) {
        #pragma unroll
        for (int u = 0; u < 16; u++)
            Os[qi * DD + hh * 16 + u] = Oacc[u] * winv;   // Os rows = local queries 0..15
    }
    __syncthreads();

    int j = tid & 127;            // output column
    int half2 = tid >> 7;         // row-halves 0/1 -> nn 0..7 / 8..15
    const float* wrow = P + OFF_OUTW + j * DD;
    float obias = P[OFF_OUTB + j];
    for (int nn = half2 * 8; nn < half2 * 8 + 8; nn++) {
        float a = (b > 0) ? obias : 0.f;
        for (int dc = 0; dc < DD; dc += 8) {
            float4 w0 = *(const float4*)&wrow[dc];
            float4 w1 = *(const float4*)&wrow[dc + 4];
            float4 o0 = *(float4*)&Os[nn * DD + dc];
            float4 o1 = *(float4*)&Os[nn * DD + dc + 4];
            a += o0.x*w0.x + o0.y*w0.y + o0.z*w0.z + o0.w*w0.w
               + o1.x*w1.x + o1.y*w1.y + o1.z*w1.z + o1.w*w1.w;
        }
        int nng = n0 + nn;
        float cs = C[b * (NV * DD) + nng * DD + j] + a;
        Cstar[b * (NV * DD) + nng * DD + j] = cs;
        store_out(dout, 524288 + b * (NV * DD) + nng * DD + j, cs, obf);
    }
}

// ===================== decoder: fused init + operand-swapped MFMA recurrence =====================
// Same anti-phased even/odd wave schedules as enc.
__global__ __launch_bounds__(512, 2) void dec_kernel(
    const float* __restrict__ Cstar,
    const void* __restrict__ iHw, const void* __restrict__ iCw,
    const void* __restrict__ Wraw,
    const float* __restrict__ P, void* __restrict__ out)
{
    const int n = blockIdx.y, b0 = blockIdx.x * BT;
    const int tid = threadIdx.x;
    const int w = tid >> 6, lane = tid & 63;
    const int l15 = lane & 15, quad = lane >> 4;
    const int obf = P[OFF_FLAGS + 0] > 0.5f;
    const int hbf = P[OFF_FLAGS + 2] > 0.5f;
    const int cbf = P[OFF_FLAGS + 3] > 0.5f;
    const int wbf = P[OFF_FLAGS + 4] > 0.5f;
    const int bown = b0 + l15;

    __shared__ alignas(16) ushort_t hS[2][16 * 136];

    // ---- fused init: D[e-row][b-col] = Cst.W^T + b ----
    bf16x8 cstB[4];
    #pragma unroll
    for (int kc = 0; kc < 4; kc++) {
        const float* cp = &Cstar[bown * (NV * DD) + n * DD + 32 * kc + 8 * quad];
        cstB[kc] = pack8(*(const f32x4*)&cp[0], *(const f32x4*)&cp[4]);
    }
    float cst[4];
    {
        f32x4 hAcc = *(const f32x4*)&P[OFF_IHB + n * DD + 16 * w + 4 * quad];
        f32x4 cAcc = *(const f32x4*)&P[OFF_ICB + n * DD + 16 * w + 4 * quad];
        #pragma unroll
        for (int kc = 0; kc < 4; kc++) {
            const int base = (n * DD + 16 * w + l15) * DD + 32 * kc + 8 * quad;
            bf16x8 wA;
            if (hbf) wA = *(const bf16x8*)((const ushort_t*)iHw + base);
            else {
                const float* fp = (const float*)iHw + base;
                wA = pack8(*(const f32x4*)fp, *(const f32x4*)(fp + 4));
            }
            hAcc = __builtin_amdgcn_mfma_f32_16x16x32_bf16(wA, cstB[kc], hAcc, 0, 0, 0);
            if (cbf) wA = *(const bf16x8*)((const ushort_t*)iCw + base);
            else {
                const float* fp = (const float*)iCw + base;
                wA = pack8(*(const f32x4*)fp, *(const f32x4*)(fp + 4));
            }
            cAcc = __builtin_amdgcn_mfma_f32_16x16x32_bf16(wA, cstB[kc], cAcc, 0, 0, 0);
        }
        float h0 = tanh_f(hAcc[0]), h1 = tanh_f(hAcc[1]);
        float h2 = tanh_f(hAcc[2]), h3 = tanh_f(hAcc[3]);
        #pragma unroll
        for (int r = 0; r < 4; r++) cst[r] = tanh_f(cAcc[r]);
        uint2 hw;
        hw.x = cvt_pk_bf16(h0, h1);
        hw.y = cvt_pk_bf16(h2, h3);
        *(uint2*)&hS[0][l15 * 136 + 16 * w + 4 * quad] = hw;
    }

    // ---- recurrence weights (A-operand) ----
    bf16x8 afrag[4][4];
    #pragma unroll
    for (int typ = 0; typ < 4; typ++) {
        const int g = typ * 128 + 16 * w + l15;
        #pragma unroll
        for (int kc = 0; kc < 4; kc++) {
            const int base = (n * G4 + g) * DD + 32 * kc + 8 * quad;
            if (wbf) {
                afrag[typ][kc] = *(const bf16x8*)((const ushort_t*)Wraw + base);
            } else {
                const float* fp = (const float*)Wraw + base;
                afrag[typ][kc] = pack8(*(const f32x4*)fp, *(const f32x4*)(fp + 4));
            }
        }
    }

    // out-proj A-fragment: row 0 = ow (every wave holds it; out-proj rotates per step)
    bf16x8 pfrag[4];
    #pragma unroll
    for (int kc = 0; kc < 4; kc++) {
        bf16x8 tmp;
        #pragma unroll
        for (int j = 0; j < 8; j++)
            tmp[j] = (l15 == 0) ? (short)f2bf(P[OFF_DOW + n * DD + 32 * kc + 8 * quad + j]) : (short)0;
        pfrag[kc] = tmp;
    }

    f32x4 bias4[4];
    #pragma unroll
    for (int typ = 0; typ < 4; typ++) {
        int base = n * G4 + typ * 128 + 16 * w + 4 * quad;
        f32x4 b1 = *(const f32x4*)&P[OFF_DBIH + base];
        f32x4 b2 = *(const f32x4*)&P[OFF_DBHH + base];
        bias4[typ] = b1 + b2;
    }
    const float ob_r = P[OFF_DOB + n];
    const f32x4 ob4 = {ob_r, ob_r, ob_r, ob_r};

    // static priority asymmetry: per SIMD one hi-prio and one lo-prio wave
    if (w & 4) __builtin_amdgcn_s_setprio(1);

#define DEC_HEAD(T, RB)                                                              \
        LBAR();                                                                      \
        bf16x8 bh[4];                                                                \
        _Pragma("unroll")                                                            \
        for (int kc = 0; kc < 4; kc++)                                               \
            bh[kc] = *(const bf16x8*)&hS[RB][l15 * 136 + 32 * kc + 8 * quad];

#define DEC_OUTPROJ(T)                                                               \
        if (w == ((T) & 7)) {                                                        \
            f32x4 accP = __builtin_amdgcn_mfma_f32_16x16x32_bf16(pfrag[0], bh[0], ob4, 0, 0, 0); \
            _Pragma("unroll")                                                        \
            for (int kc = 1; kc < 4; kc++)                                           \
                accP = __builtin_amdgcn_mfma_f32_16x16x32_bf16(pfrag[kc], bh[kc], accP, 0, 0, 0); \
            if ((T) > 0 && quad == 0)                                                \
                store_out(out, (long)bown * 4064 + (long)((T) - 1) * NV + n, accP[0], obf); \
        }

#define DEC_TAIL(T, RB)                                                              \
        uint2 hw;                                                                    \
        hw.x = cvt_pk_bf16(hh[0], hh[1]);                                            \
        hw.y = cvt_pk_bf16(hh[2], hh[3]);                                            \
        *(uint2*)&hS[(RB) ^ 1][l15 * 136 + 16 * w + 4 * quad] = hw;

// variant A (even waves): monolithic
#define DEC_STEP_A(T, RB)                                                            \
    do {                                                                             \
        DEC_HEAD(T, RB)                                                              \
        f32x4 acc[4];                                                                \
        _Pragma("unroll")                                                            \
        for (int typ = 0; typ < 4; typ++)                                            \
            acc[typ] = __builtin_amdgcn_mfma_f32_16x16x32_bf16(afrag[typ][0], bh[0], bias4[typ], 0, 0, 0); \
        _Pragma("unroll")                                                            \
        for (int kc = 1; kc < 4; kc++)                                               \
            _Pragma("unroll")                                                        \
            for (int typ = 0; typ < 4; typ++)                                        \
                acc[typ] = __builtin_amdgcn_mfma_f32_16x16x32_bf16(afrag[typ][kc], bh[kc], acc[typ], 0, 0, 0); \
        DEC_OUTPROJ(T)                                                               \
        float hh[4];                                                                 \
        _Pragma("unroll")                                                            \
        for (int r = 0; r < 4; r++) {                                                \
            float ii = sigmoid_f(acc[0][r]);                                         \
            float ff = sigmoid_f(acc[1][r]);                                         \
            float g2 = tanh_f(acc[2][r]);                                            \
            float oo = sigmoid_f(acc[3][r]);                                         \
            float cc = ff * cst[r] + ii * g2;                                        \
            cst[r] = cc;                                                             \
            hh[r] = oo * tanh_f(cc);                                                 \
        }                                                                            \
        DEC_TAIL(T, RB)                                                              \
    } while (0)

// variant B (odd waves): split gate-groups
#define DEC_STEP_B(T, RB)                                                            \
    do {                                                                             \
        DEC_HEAD(T, RB)                                                              \
        f32x4 a0 = __builtin_amdgcn_mfma_f32_16x16x32_bf16(afrag[0][0], bh[0], bias4[0], 0, 0, 0); \
        f32x4 a1 = __builtin_amdgcn_mfma_f32_16x16x32_bf16(afrag[1][0], bh[0], bias4[1], 0, 0, 0); \
        _Pragma("unroll")                                                            \
        for (int kc = 1; kc < 4; kc++) {                                             \
            a0 = __builtin_amdgcn_mfma_f32_16x16x32_bf16(afrag[0][kc], bh[kc], a0, 0, 0, 0); \
            a1 = __builtin_amdgcn_mfma_f32_16x16x32_bf16(afrag[1][kc], bh[kc], a1, 0, 0, 0); \
        }                                                                            \
        float e_i[4], e_f[4];                                                        \
        _Pragma("unroll")                                                            \
        for (int r = 0; r < 4; r++) {                                                \
            e_i[r] = exp2_f(a0[r] * L1C);                                            \
            e_f[r] = exp2_f(a1[r] * L1C);                                            \
        }                                                                            \
        f32x4 a2 = __builtin_amdgcn_mfma_f32_16x16x32_bf16(afrag[2][0], bh[0], bias4[2], 0, 0, 0); \
        f32x4 a3 = __builtin_amdgcn_mfma_f32_16x16x32_bf16(afrag[3][0], bh[0], bias4[3], 0, 0, 0); \
        _Pragma("unroll")                                                            \
        for (int kc = 1; kc < 4; kc++) {                                             \
            a2 = __builtin_amdgcn_mfma_f32_16x16x32_bf16(afrag[2][kc], bh[kc], a2, 0, 0, 0); \
            a3 = __builtin_amdgcn_mfma_f32_16x16x32_bf16(afrag[3][kc], bh[kc], a3, 0, 0, 0); \
        }                                                                            \
        DEC_OUTPROJ(T)                                                               \
        float e_g[4], e_o[4];                                                        \
        _Pragma("unroll")                                                            \
        for (int r = 0; r < 4; r++) {                                                \
            e_g[r] = exp2_f(a2[r] * L2C);                                            \
            e_o[r] = exp2_f(a3[r] * L1C);                                            \
        }                                                                            \
        float hh[4];                                                                 \
        _Pragma("unroll")                                                            \
        for (int r = 0; r < 4; r++) {                                                \
            float ii = __builtin_amdgcn_rcpf(1.f + e_i[r]);                          \
            float ff = __builtin_amdgcn_rcpf(1.f + e_f[r]);                          \
            float g2 = 1.f - 2.f * __builtin_amdgcn_rcpf(e_g[r] + 1.f);              \
            float oo = __builtin_amdgcn_rcpf(1.f + e_o[r]);                          \
            float cc = ff * cst[r] + ii * g2;                                        \
            cst[r] = cc;                                                             \
            hh[r] = oo * tanh_f(cc);                                                 \
        }                                                                            \
        DEC_TAIL(T, RB)                                                              \
    } while (0)

    if (w & 1) {
        for (int tp = 0; tp < 64; tp++) {
            DEC_STEP_B(2 * tp, 0);
            DEC_STEP_B(2 * tp + 1, 1);
        }
    } else {
        for (int tp = 0; tp < 64; tp++) {
            DEC_STEP_A(2 * tp, 0);
            DEC_STEP_A(2 * tp + 1, 1);
        }
    }
#undef DEC_STEP_A
#undef DEC_STEP_B
#undef DEC_HEAD
#undef DEC_OUTPROJ
#undef DEC_TAIL

    // o_127 from h_127 (t=127 wrote hS[0]); 128 & 7 == 0 -> wave 0, consistent with rotation
    LBAR();
    if (w == 0) {
        f32x4 accP = __builtin_amdgcn_mfma_f32_16x16x32_bf16(
            pfrag[0], *(const bf16x8*)&hS[0][l15 * 136 + 8 * quad], ob4, 0, 0, 0);
        #pragma unroll
        for (int kc = 1; kc < 4; kc++) {
            bf16x8 bh = *(const bf16x8*)&hS[0][l15 * 136 + 32 * kc + 8 * quad];
            accP = __builtin_amdgcn_mfma_f32_16x16x32_bf16(pfrag[kc], bh, accP, 0, 0, 0);
        }
        if (quad == 0)
            store_out(out, 520192 + (long)bown * NV + n, accP[0], obf);
    }
}

extern "C" void kernel_launch(void* const* d_in, const int* in_sizes, int n_in,
                              void* d_out, int out_size, void* d_ws, size_t ws_size,
                              hipStream_t stream) {
    char* ws = (char*)d_ws;
    float*    P    = (float*)(ws + 0);              // ~595 KB
    float*    Xc   = (float*)(ws + (1u << 20));     // 2 MB
    float*    C    = (float*)(ws + (3u << 20));     // 2 MB
    float*    qb   = (float*)(ws + (5u << 20));
    float*    kb   = (float*)(ws + (7u << 20));
    float*    vb   = (float*)(ws + (9u << 20));
    float*    Cst  = (float*)(ws + (11u << 20));

    Ptr19 a;
    for (int i = 0; i < 19; i++) a.p[i] = d_in[i];

    prep_kernel<<<842, 256, 0, stream>>>(a, P, Xc);
    enc_kernel<<<dim3(8, 32), 512, 0, stream>>>(Xc, d_in[2], P, C);
    qkv_kernel<<<dim3(128, 3), 256, 0, stream>>>(C, P, qb, kb, vb);
    attn_kernel<<<dim3(128, 2), 256, 0, stream>>>(qb, kb, vb, C, P, Cst, d_out);
    dec_kernel<<<dim3(8, 32), 512, 0, stream>>>(Cst, d_in[10], d_in[12], d_in[14], P, d_out);
}

// Round 10
// 409.030 us; speedup vs baseline: 1.0249x; 1.0044x over previous
//
#include <hip/hip_runtime.h>
#include <hip/hip_bf16.h>

typedef unsigned short ushort_t;
typedef unsigned int uint_t;

#define DD   128
#define G4   512
#define BT   16
#define NB   128
#define NV   32

// param block offsets (floats), each section 256-aligned so prep blocks map 1:1 to sources
#define OFF_WIH   0
#define OFF_EB    16384
#define OFF_PW    32768
#define OFF_PB    36864
#define OFF_INW   37120
#define OFF_INB   86272
#define OFF_OUTW  86784
#define OFF_OUTB  103168
#define OFF_IHB   103424
#define OFF_ICB   107520
#define OFF_DBIH  111616
#define OFF_DBHH  128000
#define OFF_DOW   144384
#define OFF_DOB   148480
#define P_TOTAL   148736   // = 581 * 256
// dtype flags stashed in PB-section padding: [32]=X, [33]=eWhh, [34]=iHw, [35]=iCw, [36]=dWhh
#define OFF_FLAGS (OFF_PB + 32)

typedef __attribute__((ext_vector_type(8))) short bf16x8;
typedef __attribute__((ext_vector_type(4))) float f32x4;

__device__ __forceinline__ float bf2f(ushort_t u) {
    union { uint_t i; float f; } x; x.i = ((uint_t)u) << 16; return x.f;
}
__device__ __forceinline__ ushort_t f2bf(float f) {
    __hip_bfloat16 h = __float2bfloat16(f);   // RNE
    return *(ushort_t*)&h;
}
__device__ __forceinline__ uint_t f2u(float f) {
    union { float f; uint_t i; } x; x.f = f; return x.i;
}
__device__ __forceinline__ float u2f(uint_t u) {
    union { uint_t i; float f; } x; x.i = u; return x.f;
}
// raw v_exp_f32 (2^x)
__device__ __forceinline__ float exp2_f(float x) {
    float r; asm("v_exp_f32 %0, %1" : "=v"(r) : "v"(x)); return r;
}
#define L1C (-1.442695041f)
#define L2C (2.885390082f)
// sigmoid(x) = rcp(1 + 2^(-x*log2e))  -- saturates gracefully at both ends
__device__ __forceinline__ float sigmoid_f(float x) {
    return __builtin_amdgcn_rcpf(1.f + exp2_f(x * L1C));
}
// tanh(x) = 1 - 2*rcp(2^(2x*log2e)+1) -- saturates gracefully (rcp(inf)=0 -> 1)
__device__ __forceinline__ float tanh_f(float x) {
    return 1.f - 2.f * __builtin_amdgcn_rcpf(exp2_f(x * L2C) + 1.f);
}
// packed f32 -> 2x bf16 (RNE), guaranteed 1 instr
__device__ __forceinline__ uint_t cvt_pk_bf16(float a, float b) {
    uint_t r; asm("v_cvt_pk_bf16_f32 %0, %1, %2" : "=v"(r) : "v"(a), "v"(b)); return r;
}
__device__ __forceinline__ bf16x8 pack8(f32x4 a, f32x4 b) {
    union { uint_t u[4]; bf16x8 v; } x;
    x.u[0] = cvt_pk_bf16(a.x, a.y); x.u[1] = cvt_pk_bf16(a.z, a.w);
    x.u[2] = cvt_pk_bf16(b.x, b.y); x.u[3] = cvt_pk_bf16(b.z, b.w);
    return x.v;
}
__device__ __forceinline__ float swz_bcast_l15(float v) {
    // BitMode and=0x0F: new_lane = lane & 15 (within each 32-lane half)
    return u2f((uint_t)__builtin_amdgcn_ds_swizzle((int)f2u(v), 0x000F));
}
__device__ __forceinline__ void store_out(void* out, long idx, float v, int bf) {
    if (bf) ((ushort_t*)out)[idx] = f2bf(v);
    else    ((float*)out)[idx]    = v;
}
// light barrier: drain LDS only; global loads/stores stay in flight across it.
#define LBAR() do { asm volatile("s_waitcnt lgkmcnt(0)" ::: "memory"); \
                    __builtin_amdgcn_s_barrier(); } while (0)

// per-wave dtype probe: 1 if data looks bf16 when read as ushort
__device__ __forceinline__ int wave_probe(const void* p, int elems) {
    int cap = elems < 1024 ? elems : 1024;
    int lane = threadIdx.x & 63;
    const ushort_t* u = (const ushort_t*)p;
    int cnt = 0, tot = 0;
    for (int j = lane; j < cap; j += 64) {
        ushort_t x = u[j];
        float af = fabsf(bf2f(x));
        tot++;
        if (x == 0 || (af > 1e-7f && af < 100.f)) cnt++;
    }
    #pragma unroll
    for (int off = 32; off >= 1; off >>= 1) {
        cnt += __shfl_xor(cnt, off);
        tot += __shfl_xor(tot, off);
    }
    return (cnt * 10 >= tot * 9) ? 1 : 0;
}

struct Ptr19 { const void* p[19]; };

// ---------------- prep: params (581) + X transpose (256) + dtype flags (5) ----------------
__global__ __launch_bounds__(256) void prep_kernel(Ptr19 a, float* __restrict__ P,
                                                   float* __restrict__ Xc) {
    __shared__ float tile[32][65];
    if (blockIdx.x < 581) {
        int base = blockIdx.x * 256;
        int src, o0, size;
        if      (base < OFF_EB)   { src = 1;  o0 = base - OFF_WIH;  size = 16384; }
        else if (base < OFF_PW)   { src = 3;  o0 = base - OFF_EB;   size = 16384; }
        else if (base < OFF_PB)   { src = 4;  o0 = base - OFF_PW;   size = 4096;  }
        else if (base < OFF_INW)  { src = 5;  o0 = base - OFF_PB;   size = 32;    }
        else if (base < OFF_INB)  { src = 6;  o0 = base - OFF_INW;  size = 49152; }
        else if (base < OFF_OUTW) { src = 7;  o0 = base - OFF_INB;  size = 384;   }
        else if (base < OFF_OUTB) { src = 8;  o0 = base - OFF_OUTW; size = 16384; }
        else if (base < OFF_IHB)  { src = 9;  o0 = base - OFF_OUTB; size = 128;   }
        else if (base < OFF_ICB)  { src = 11; o0 = base - OFF_IHB;  size = 4096;  }
        else if (base < OFF_DBIH) { src = 13; o0 = base - OFF_ICB;  size = 4096;  }
        else if (base < OFF_DBHH) { src = 15; o0 = base - OFF_DBIH; size = 16384; }
        else if (base < OFF_DOW)  { src = 16; o0 = base - OFF_DBHH; size = 16384; }
        else if (base < OFF_DOB)  { src = 17; o0 = base - OFF_DOW;  size = 4096;  }
        else                      { src = 18; o0 = base - OFF_DOB;  size = 32;    }
        int bf = wave_probe(a.p[src], size);
        int off = o0 + (int)threadIdx.x;
        if (off < size)
            P[base + threadIdx.x] = bf ? bf2f(((const ushort_t*)a.p[src])[off])
                                       : ((const float*)a.p[src])[off];
    } else if (blockIdx.x < 837) {
        int bf = wave_probe(a.p[0], 1024);
        int idx2 = blockIdx.x - 581;
        int bt = (idx2 & 3) * 32, tn0 = (idx2 >> 2) * 64;
        const void* src = a.p[0];
        int tx = threadIdx.x & 63, ty = threadIdx.x >> 6;
        #pragma unroll
        for (int k = 0; k < 8; k++) {
            int row = ty * 8 + k;
            int idx = (bt + row) * 4096 + tn0 + tx;
            tile[row][tx] = bf ? bf2f(((const ushort_t*)src)[idx]) : ((const float*)src)[idx];
        }
        __syncthreads();
        int bx = threadIdx.x & 31, tyy = threadIdx.x >> 5;
        #pragma unroll
        for (int k = 0; k < 8; k++) {
            int tn = tn0 + tyy * 8 + k;
            int t = tn >> 5, nn = tn & 31;
            Xc[t * 4096 + nn * 128 + bt + bx] = tile[bx][tyy * 8 + k];
        }
    } else {
        int which = blockIdx.x - 837;            // 0..4
        int src = (which == 0) ? 0 : (which == 1) ? 2 : (which == 2) ? 10
                : (which == 3) ? 12 : 14;
        int flag = wave_probe(a.p[src], 1024);
        if (threadIdx.x == 0) P[OFF_FLAGS + which] = (float)flag;
    }
}

// ===================== encoder: operand-swapped MFMA recurrence =====================
// D[g-row][b-col]: thread owns (b = l15, d = 16w + 4quad + r, r=0..3).
// GRID: (32, 8) -- n = blockIdx.x, batch-chunk = blockIdx.y. Same-n blocks are 32
// apart in linear id (= 0 mod 8) -> land on the SAME XCD under round-robin dispatch,
// so each variable's 128KB weight panel is fetched ~once instead of 8x (T1).
// ANTI-PHASED even/odd wave schedules (R9); identical arithmetic both variants.
__global__ __launch_bounds__(512, 2) void enc_kernel(
    const float* __restrict__ Xc, const void* __restrict__ Wraw,
    const float* __restrict__ P, float* __restrict__ Cout)
{
    const int n = blockIdx.x, b0 = blockIdx.y * BT;
    const int tid = threadIdx.x;
    const int w = tid >> 6, lane = tid & 63;
    const int l15 = lane & 15, quad = lane >> 4;
    const int wbf = P[OFF_FLAGS + 1] > 0.5f;
    const int bown = b0 + l15;

    __shared__ alignas(16) ushort_t hS[2][16 * 136];
    for (int i = tid; i < 16 * 136; i += 512) hS[0][i] = 0;

    // A-fragments (weights): lane holds W[g = typ*128 + 16w + l15][k = 32kc+8quad+j]
    bf16x8 afrag[4][4];
    #pragma unroll
    for (int typ = 0; typ < 4; typ++) {
        const int g = typ * 128 + 16 * w + l15;
        #pragma unroll
        for (int kc = 0; kc < 4; kc++) {
            const int base = (n * G4 + g) * DD + 32 * kc + 8 * quad;
            if (wbf) {
                afrag[typ][kc] = *(const bf16x8*)((const ushort_t*)Wraw + base);
            } else {
                const float* fp = (const float*)Wraw + base;
                afrag[typ][kc] = pack8(*(const f32x4*)fp, *(const f32x4*)(fp + 4));
            }
        }
    }

    // pool A-fragment: rows 0 and 8 carry pw (so both 32-lane halves get s)
    bf16x8 pfrag[4];
    #pragma unroll
    for (int kc = 0; kc < 4; kc++) {
        bf16x8 tmp;
        #pragma unroll
        for (int j = 0; j < 8; j++)
            tmp[j] = (l15 == 0 || l15 == 8)
                   ? (short)f2bf(P[OFF_PW + n * DD + 32 * kc + 8 * quad + j]) : (short)0;
        pfrag[kc] = tmp;
    }

    f32x4 bias4[4], wih4[4];
    #pragma unroll
    for (int typ = 0; typ < 4; typ++) {
        int base = n * G4 + typ * 128 + 16 * w + 4 * quad;
        bias4[typ] = *(const f32x4*)&P[OFF_EB + base];
        wih4[typ]  = *(const f32x4*)&P[OFF_WIH + base];
    }
    const float pb_r = P[OFF_PB + n];
    const f32x4 pb4 = {pb_r, pb_r, pb_r, pb_r};

    float cst[4] = {0.f, 0.f, 0.f, 0.f};
    f32x4 hpair[2];
    hpair[0] = f32x4{0.f, 0.f, 0.f, 0.f};
    hpair[1] = f32x4{0.f, 0.f, 0.f, 0.f};
    f32x4 Cacc   = {0.f, 0.f, 0.f, 0.f};
    float lR = 0.f, pend = 0.f;

    const float* xnext = Xc + n * 128 + bown;
    float xq = *xnext;            // t = 0
    xnext += 4096;

    // static priority asymmetry: per SIMD one hi-prio and one lo-prio wave
    if (w & 4) __builtin_amdgcn_s_setprio(1);

// shared prologue: barrier, bh read, deferred pool update
#define ENC_HEAD(T, RB)                                                              \
        LBAR();                                                                      \
        bf16x8 bh[4];                                                                \
        _Pragma("unroll")                                                            \
        for (int kc = 0; kc < 4; kc++)                                               \
            bh[kc] = *(const bf16x8*)&hS[RB][l15 * 136 + 32 * kc + 8 * quad];        \
        if ((T) >= 2) {                                                              \
            float e = __expf(pend);                                                  \
            lR += e;                                                                 \
            f32x4 ev = {e, e, e, e};                                                 \
            Cacc += ev * hpair[RB];                                                  \
        }                                                                            \
        f32x4 xv = {xq, xq, xq, xq};

// shared epilogue: h store + history
#define ENC_TAIL(T, RB)                                                              \
        hpair[RB].x = hh[0]; hpair[RB].y = hh[1];                                    \
        hpair[RB].z = hh[2]; hpair[RB].w = hh[3];                                    \
        uint2 hw;                                                                    \
        hw.x = cvt_pk_bf16(hh[0], hh[1]);                                            \
        hw.y = cvt_pk_bf16(hh[2], hh[3]);                                            \
        *(uint2*)&hS[(RB) ^ 1][l15 * 136 + 16 * w + 4 * quad] = hw;

// variant A (even waves): monolithic — all 20 MFMAs, then the whole trans burst
#define ENC_STEP_A(T, RB)                                                            \
    do {                                                                             \
        ENC_HEAD(T, RB)                                                              \
        f32x4 acc[4];                                                                \
        _Pragma("unroll")                                                            \
        for (int typ = 0; typ < 4; typ++)                                            \
            acc[typ] = __builtin_amdgcn_mfma_f32_16x16x32_bf16(                      \
                afrag[typ][0], bh[0], bias4[typ] + xv * wih4[typ], 0, 0, 0);         \
        f32x4 aP = __builtin_amdgcn_mfma_f32_16x16x32_bf16(pfrag[0], bh[0], pb4, 0, 0, 0); \
        xq = *xnext; xnext += 4096;                                                  \
        _Pragma("unroll")                                                            \
        for (int kc = 1; kc < 4; kc++) {                                             \
            aP = __builtin_amdgcn_mfma_f32_16x16x32_bf16(pfrag[kc], bh[kc], aP, 0, 0, 0); \
            _Pragma("unroll")                                                        \
            for (int typ = 0; typ < 4; typ++)                                        \
                acc[typ] = __builtin_amdgcn_mfma_f32_16x16x32_bf16(afrag[typ][kc], bh[kc], acc[typ], 0, 0, 0); \
        }                                                                            \
        if ((T) >= 1) pend = swz_bcast_l15(aP[0]);                                   \
        float hh[4];                                                                 \
        _Pragma("unroll")                                                            \
        for (int r = 0; r < 4; r++) {                                                \
            float ii = sigmoid_f(acc[0][r]);                                         \
            float ff = sigmoid_f(acc[1][r]);                                         \
            float g2 = tanh_f(acc[2][r]);                                            \
            float oo = sigmoid_f(acc[3][r]);                                         \
            float cc = ff * cst[r] + ii * g2;                                        \
            cst[r] = cc;                                                             \
            hh[r] = oo * tanh_f(cc);                                                 \
        }                                                                            \
        ENC_TAIL(T, RB)                                                              \
    } while (0)

// variant B (odd waves): split — {i,f} MFMAs -> their exp2s -> {g,o,P} MFMAs -> theirs
#define ENC_STEP_B(T, RB)                                                            \
    do {                                                                             \
        ENC_HEAD(T, RB)                                                              \
        f32x4 a0 = __builtin_amdgcn_mfma_f32_16x16x32_bf16(                          \
            afrag[0][0], bh[0], bias4[0] + xv * wih4[0], 0, 0, 0);                   \
        f32x4 a1 = __builtin_amdgcn_mfma_f32_16x16x32_bf16(                          \
            afrag[1][0], bh[0], bias4[1] + xv * wih4[1], 0, 0, 0);                   \
        _Pragma("unroll")                                                            \
        for (int kc = 1; kc < 4; kc++) {                                             \
            a0 = __builtin_amdgcn_mfma_f32_16x16x32_bf16(afrag[0][kc], bh[kc], a0, 0, 0, 0); \
            a1 = __builtin_amdgcn_mfma_f32_16x16x32_bf16(afrag[1][kc], bh[kc], a1, 0, 0, 0); \
        }                                                                            \
        float e_i[4], e_f[4];                                                        \
        _Pragma("unroll")                                                            \
        for (int r = 0; r < 4; r++) {                                                \
            e_i[r] = exp2_f(a0[r] * L1C);                                            \
            e_f[r] = exp2_f(a1[r] * L1C);                                            \
        }                                                                            \
        f32x4 a2 = __builtin_amdgcn_mfma_f32_16x16x32_bf16(                          \
            afrag[2][0], bh[0], bias4[2] + xv * wih4[2], 0, 0, 0);                   \
        f32x4 a3 = __builtin_amdgcn_mfma_f32_16x16x32_bf16(                          \
            afrag[3][0], bh[0], bias4[3] + xv * wih4[3], 0, 0, 0);                   \
        f32x4 aP = __builtin_amdgcn_mfma_f32_16x16x32_bf16(pfrag[0], bh[0], pb4, 0, 0, 0); \
        xq = *xnext; xnext += 4096;                                                  \
        _Pragma("unroll")                                                            \
        for (int kc = 1; kc < 4; kc++) {                                             \
            a2 = __builtin_amdgcn_mfma_f32_16x16x32_bf16(afrag[2][kc], bh[kc], a2, 0, 0, 0); \
            a3 = __builtin_amdgcn_mfma_f32_16x16x32_bf16(afrag[3][kc], bh[kc], a3, 0, 0, 0); \
            aP = __builtin_amdgcn_mfma_f32_16x16x32_bf16(pfrag[kc], bh[kc], aP, 0, 0, 0); \
        }                                                                            \
        float e_g[4], e_o[4];                                                        \
        _Pragma("unroll")                                                            \
        for (int r = 0; r < 4; r++) {                                                \
            e_g[r] = exp2_f(a2[r] * L2C);                                            \
            e_o[r] = exp2_f(a3[r] * L1C);                                            \
        }                                                                            \
        if ((T) >= 1) pend = swz_bcast_l15(aP[0]);                                   \
        float hh[4];                                                                 \
        _Pragma("unroll")                                                            \
        for (int r = 0; r < 4; r++) {                                                \
            float ii = __builtin_amdgcn_rcpf(1.f + e_i[r]);                          \
            float ff = __builtin_amdgcn_rcpf(1.f + e_f[r]);                          \
            float g2 = 1.f - 2.f * __builtin_amdgcn_rcpf(e_g[r] + 1.f);              \
            float oo = __builtin_amdgcn_rcpf(1.f + e_o[r]);                          \
            float cc = ff * cst[r] + ii * g2;                                        \
            cst[r] = cc;                                                             \
            hh[r] = oo * tanh_f(cc);                                                 \
        }                                                                            \
        ENC_TAIL(T, RB)                                                              \
    } while (0)

    if (w & 1) {
        for (int tp = 0; tp < 63; tp++) {
            ENC_STEP_B(2 * tp, 0);
            ENC_STEP_B(2 * tp + 1, 1);
        }
        ENC_STEP_B(126, 0);
    } else {
        for (int tp = 0; tp < 63; tp++) {
            ENC_STEP_A(2 * tp, 0);
            ENC_STEP_A(2 * tp + 1, 1);
        }
        ENC_STEP_A(126, 0);
    }
#undef ENC_STEP_A
#undef ENC_STEP_B
#undef ENC_HEAD
#undef ENC_TAIL

    // final fold: consume pend(126)=score(h_125) with hpair[1]; then fresh score of
    // h_126 (in hS[1] / hpair[0]).
    LBAR();
    {
        float e = __expf(pend);
        lR += e;
        f32x4 ev = {e, e, e, e};
        Cacc += ev * hpair[1];

        f32x4 accP = __builtin_amdgcn_mfma_f32_16x16x32_bf16(
            pfrag[0], *(const bf16x8*)&hS[1][l15 * 136 + 8 * quad], pb4, 0, 0, 0);
        #pragma unroll
        for (int kc = 1; kc < 4; kc++) {
            bf16x8 bh = *(const bf16x8*)&hS[1][l15 * 136 + 32 * kc + 8 * quad];
            accP = __builtin_amdgcn_mfma_f32_16x16x32_bf16(pfrag[kc], bh, accP, 0, 0, 0);
        }
        float e2 = __expf(swz_bcast_l15(accP[0]));
        lR += e2;
        f32x4 ev2 = {e2, e2, e2, e2};
        Cacc += ev2 * hpair[0];
    }
    float inv = 1.f / lR;
    f32x4 iv = {inv, inv, inv, inv};
    f32x4 cv = Cacc * iv;
    *(f32x4*)&Cout[bown * (NV * DD) + n * DD + 16 * w + 4 * quad] = cv;
}

// ---------------- QKV projection ----------------
__global__ __launch_bounds__(256) void qkv_kernel(
    const float* __restrict__ C, const float* __restrict__ P,
    float* __restrict__ q, float* __restrict__ k, float* __restrict__ v)
{
    int b = blockIdx.x, p = blockIdx.y, tid = threadIdx.x;
    int j = tid & 127, half = tid >> 7;
    __shared__ float Cb[NV * DD];
    for (int i = tid; i < NV * DD; i += 256) Cb[i] = C[b * (NV * DD) + i];
    __syncthreads();

    const float* wrow = P + OFF_INW + (p * DD + j) * DD;
    float bias = P[OFF_INB + p * DD + j];
    float acc[16];
    #pragma unroll
    for (int nn = 0; nn < 16; nn++) acc[nn] = bias;

    for (int dc = 0; dc < DD; dc += 8) {
        float4 w0 = *(const float4*)&wrow[dc];
        float4 w1 = *(const float4*)&wrow[dc + 4];
        #pragma unroll
        for (int nn = 0; nn < 16; nn++) {
            const float* cb = &Cb[(half * 16 + nn) * DD + dc];
            float4 c0 = *(float4*)&cb[0];
            float4 c1 = *(float4*)&cb[4];
            acc[nn] += c0.x * w0.x + c0.y * w0.y + c0.z * w0.z + c0.w * w0.w
                     + c1.x * w1.x + c1.y * w1.y + c1.z * w1.z + c1.w * w1.w;
        }
    }
    float* dst = (p == 0) ? q : (p == 1) ? k : v;
    for (int nn = 0; nn < 16; nn++)
        dst[b * (NV * DD) + (half * 16 + nn) * DD + j] = acc[nn];
}

// ---------------- cross-attention + out-proj + residual, split by query-half ----------------
// 256 threads: thread = (hh = tid>>5, sub = (tid>>4)&1, qi = tid&15); each sub owns
// 16 of the 32 keys; max/denominator/Oacc combined via shfl_xor(.,16).
__global__ __launch_bounds__(256) void attn_kernel(
    const float* __restrict__ q, const float* __restrict__ k, const float* __restrict__ v,
    const float* __restrict__ C, const float* __restrict__ P,
    float* __restrict__ Cstar, void* __restrict__ dout)
{
    int b = blockIdx.x, half = blockIdx.y, tid = threadIdx.x;
    int obf = P[OFF_FLAGS + 0] > 0.5f;
    int n0 = half * 16;
    __shared__ float Qs[16 * DD], Ks[NV * DD], Vs[NV * DD];
    float* Os = Ks;   // reused after last Ks read (sync-separated)
    for (int i = tid; i < 16 * DD; i += 256) Qs[i] = q[b * (NV * DD) + n0 * DD + i];
    __syncthreads();

    int qi = tid & 15, sub = (tid >> 4) & 1, hh = tid >> 5;   // 8 heads x 2 subs x 16 queries
    int kk0 = sub * 16;
    float qreg[16];
    #pragma unroll
    for (int u = 0; u < 4; u++) {
        float4 t4 = *(float4*)&Qs[qi * DD + hh * 16 + 4 * u];
        qreg[4*u] = t4.x; qreg[4*u+1] = t4.y; qreg[4*u+2] = t4.z; qreg[4*u+3] = t4.w;
    }

    float Oacc[16];
    #pragma unroll
    for (int u = 0; u < 16; u++) Oacc[u] = 0.f;
    float wsum = 0.f;
    int tmax = (b < 5) ? b : 5;

    // reg prefetch buffers: 4 float4 each (1024 float4 per array / 256 threads)
    float4 kr[4], vr[4];
#define ATT_LOAD(TAU)                                                            \
    do {                                                                         \
        const float4* kp = (const float4*)&k[(b - (TAU)) * (NV * DD)];           \
        const float4* vp = (const float4*)&v[(b - (TAU)) * (NV * DD)];           \
        _Pragma("unroll")                                                        \
        for (int u = 0; u < 4; u++) {                                            \
            kr[u] = kp[tid + 256 * u];                                           \
            vr[u] = vp[tid + 256 * u];                                           \
        }                                                                        \
    } while (0)

    if (tmax >= 1) ATT_LOAD(1);

    for (int tau = 1; tau <= tmax; tau++) {
        __syncthreads();
        #pragma unroll
        for (int u = 0; u < 4; u++) {
            ((float4*)Ks)[tid + 256 * u] = kr[u];
            ((float4*)Vs)[tid + 256 * u] = vr[u];
        }
        __syncthreads();
        if (tau < tmax) ATT_LOAD(tau + 1);   // issue next-tau loads; hide under compute

        float s[16];
        #pragma unroll
        for (int kk = 0; kk < 16; kk++) {
            float a = 0.f;
            #pragma unroll
            for (int u = 0; u < 4; u++) {
                float4 kv = *(float4*)&Ks[(kk0 + kk) * DD + hh * 16 + 4 * u];
                a += qreg[4*u] * kv.x + qreg[4*u+1] * kv.y
                   + qreg[4*u+2] * kv.z + qreg[4*u+3] * kv.w;
            }
            s[kk] = a * 0.25f;
        }
        float mm = s[0];
        #pragma unroll
        for (int kk = 1; kk < 16; kk++) mm = fmaxf(mm, s[kk]);
        mm = fmaxf(mm, __shfl_xor(mm, 16));          // full 32-key max
        float ssum = 0.f;
        #pragma unroll
        for (int kk = 0; kk < 16; kk++) { s[kk] = __expf(s[kk] - mm); ssum += s[kk]; }
        ssum += __shfl_xor(ssum, 16);                // full 32-key denom
        float wdk = __expf(-0.7f * (float)(tau - 1));
        wsum += wdk;
        float wr = wdk / ssum;
        #pragma unroll
        for (int u = 0; u < 4; u++) {
            float ax = 0.f, ay = 0.f, az = 0.f, aw = 0.f;
            #pragma unroll
            for (int kk = 0; kk < 16; kk++) {
                float4 vv = *(float4*)&Vs[(kk0 + kk) * DD + hh * 16 + 4 * u];
                ax += s[kk] * vv.x; ay += s[kk] * vv.y;
                az += s[kk] * vv.z; aw += s[kk] * vv.w;
            }
            Oacc[4*u] += wr * ax; Oacc[4*u+1] += wr * ay;
            Oacc[4*u+2] += wr * az; Oacc[4*u+3] += wr * aw;
        }
    }
#undef ATT_LOAD

    // combine the two key-halves
    #pragma unroll
    for (int u = 0; u < 16; u++) Oacc[u] += __shfl_xor(Oacc[u], 16);

    __syncthreads();
    float winv = (b > 0) ? 1.f / wsum : 0.f;
    if (sub == 0) {
        #pragma unroll
        for (int u = 0; u < 16; u++)
            Os[qi * DD + hh * 16 + u] = Oacc[u] * winv;   // Os rows = local queries 0..15
    }
    __syncthreads();

    int j = tid & 127;            // output column
    int half2 = tid >> 7;         // row-halves 0/1 -> nn 0..7 / 8..15
    const float* wrow = P + OFF_OUTW + j * DD;
    float obias = P[OFF_OUTB + j];
    for (int nn = half2 * 8; nn < half2 * 8 + 8; nn++) {
        float a = (b > 0) ? obias : 0.f;
        for (int dc = 0; dc < DD; dc += 8) {
            float4 w0 = *(const float4*)&wrow[dc];
            float4 w1 = *(const float4*)&wrow[dc + 4];
            float4 o0 = *(float4*)&Os[nn * DD + dc];
            float4 o1 = *(float4*)&Os[nn * DD + dc + 4];
            a += o0.x*w0.x + o0.y*w0.y + o0.z*w0.z + o0.w*w0.w
               + o1.x*w1.x + o1.y*w1.y + o1.z*w1.z + o1.w*w1.w;
        }
        int nng = n0 + nn;
        float cs = C[b * (NV * DD) + nng * DD + j] + a;
        Cstar[b * (NV * DD) + nng * DD + j] = cs;
        store_out(dout, 524288 + b * (NV * DD) + nng * DD + j, cs, obf);
    }
}

// ===================== decoder: fused init + operand-swapped MFMA recurrence =====================
// GRID: (32, 8) -- n = blockIdx.x (same-n blocks co-locate per XCD, T1), like enc.
// Same anti-phased even/odd wave schedules as enc.
__global__ __launch_bounds__(512, 2) void dec_kernel(
    const float* __restrict__ Cstar,
    const void* __restrict__ iHw, const void* __restrict__ iCw,
    const void* __restrict__ Wraw,
    const float* __restrict__ P, void* __restrict__ out)
{
    const int n = blockIdx.x, b0 = blockIdx.y * BT;
    const int tid = threadIdx.x;
    const int w = tid >> 6, lane = tid & 63;
    const int l15 = lane & 15, quad = lane >> 4;
    const int obf = P[OFF_FLAGS + 0] > 0.5f;
    const int hbf = P[OFF_FLAGS + 2] > 0.5f;
    const int cbf = P[OFF_FLAGS + 3] > 0.5f;
    const int wbf = P[OFF_FLAGS + 4] > 0.5f;
    const int bown = b0 + l15;

    __shared__ alignas(16) ushort_t hS[2][16 * 136];

    // ---- fused init: D[e-row][b-col] = Cst.W^T + b ----
    bf16x8 cstB[4];
    #pragma unroll
    for (int kc = 0; kc < 4; kc++) {
        const float* cp = &Cstar[bown * (NV * DD) + n * DD + 32 * kc + 8 * quad];
        cstB[kc] = pack8(*(const f32x4*)&cp[0], *(const f32x4*)&cp[4]);
    }
    float cst[4];
    {
        f32x4 hAcc = *(const f32x4*)&P[OFF_IHB + n * DD + 16 * w + 4 * quad];
        f32x4 cAcc = *(const f32x4*)&P[OFF_ICB + n * DD + 16 * w + 4 * quad];
        #pragma unroll
        for (int kc = 0; kc < 4; kc++) {
            const int base = (n * DD + 16 * w + l15) * DD + 32 * kc + 8 * quad;
            bf16x8 wA;
            if (hbf) wA = *(const bf16x8*)((const ushort_t*)iHw + base);
            else {
                const float* fp = (const float*)iHw + base;
                wA = pack8(*(const f32x4*)fp, *(const f32x4*)(fp + 4));
            }
            hAcc = __builtin_amdgcn_mfma_f32_16x16x32_bf16(wA, cstB[kc], hAcc, 0, 0, 0);
            if (cbf) wA = *(const bf16x8*)((const ushort_t*)iCw + base);
            else {
                const float* fp = (const float*)iCw + base;
                wA = pack8(*(const f32x4*)fp, *(const f32x4*)(fp + 4));
            }
            cAcc = __builtin_amdgcn_mfma_f32_16x16x32_bf16(wA, cstB[kc], cAcc, 0, 0, 0);
        }
        float h0 = tanh_f(hAcc[0]), h1 = tanh_f(hAcc[1]);
        float h2 = tanh_f(hAcc[2]), h3 = tanh_f(hAcc[3]);
        #pragma unroll
        for (int r = 0; r < 4; r++) cst[r] = tanh_f(cAcc[r]);
        uint2 hw;
        hw.x = cvt_pk_bf16(h0, h1);
        hw.y = cvt_pk_bf16(h2, h3);
        *(uint2*)&hS[0][l15 * 136 + 16 * w + 4 * quad] = hw;
    }

    // ---- recurrence weights (A-operand) ----
    bf16x8 afrag[4][4];
    #pragma unroll
    for (int typ = 0; typ < 4; typ++) {
        const int g = typ * 128 + 16 * w + l15;
        #pragma unroll
        for (int kc = 0; kc < 4; kc++) {
            const int base = (n * G4 + g) * DD + 32 * kc + 8 * quad;
            if (wbf) {
                afrag[typ][kc] = *(const bf16x8*)((const ushort_t*)Wraw + base);
            } else {
                const float* fp = (const float*)Wraw + base;
                afrag[typ][kc] = pack8(*(const f32x4*)fp, *(const f32x4*)(fp + 4));
            }
        }
    }

    // out-proj A-fragment: row 0 = ow (every wave holds it; out-proj rotates per step)
    bf16x8 pfrag[4];
    #pragma unroll
    for (int kc = 0; kc < 4; kc++) {
        bf16x8 tmp;
        #pragma unroll
        for (int j = 0; j < 8; j++)
            tmp[j] = (l15 == 0) ? (short)f2bf(P[OFF_DOW + n * DD + 32 * kc + 8 * quad + j]) : (short)0;
        pfrag[kc] = tmp;
    }

    f32x4 bias4[4];
    #pragma unroll
    for (int typ = 0; typ < 4; typ++) {
        int base = n * G4 + typ * 128 + 16 * w + 4 * quad;
        f32x4 b1 = *(const f32x4*)&P[OFF_DBIH + base];
        f32x4 b2 = *(const f32x4*)&P[OFF_DBHH + base];
        bias4[typ] = b1 + b2;
    }
    const float ob_r = P[OFF_DOB + n];
    const f32x4 ob4 = {ob_r, ob_r, ob_r, ob_r};

    // static priority asymmetry: per SIMD one hi-prio and one lo-prio wave
    if (w & 4) __builtin_amdgcn_s_setprio(1);

#define DEC_HEAD(T, RB)                                                              \
        LBAR();                                                                      \
        bf16x8 bh[4];                                                                \
        _Pragma("unroll")                                                            \
        for (int kc = 0; kc < 4; kc++)                                               \
            bh[kc] = *(const bf16x8*)&hS[RB][l15 * 136 + 32 * kc + 8 * quad];

#define DEC_OUTPROJ(T)                                                               \
        if (w == ((T) & 7)) {                                                        \
            f32x4 accP = __builtin_amdgcn_mfma_f32_16x16x32_bf16(pfrag[0], bh[0], ob4, 0, 0, 0); \
            _Pragma("unroll")                                                        \
            for (int kc = 1; kc < 4; kc++)                                           \
                accP = __builtin_amdgcn_mfma_f32_16x16x32_bf16(pfrag[kc], bh[kc], accP, 0, 0, 0); \
            if ((T) > 0 && quad == 0)                                                \
                store_out(out, (long)bown * 4064 + (long)((T) - 1) * NV + n, accP[0], obf); \
        }

#define DEC_TAIL(T, RB)                                                              \
        uint2 hw;                                                                    \
        hw.x = cvt_pk_bf16(hh[0], hh[1]);                                            \
        hw.y = cvt_pk_bf16(hh[2], hh[3]);                                            \
        *(uint2*)&hS[(RB) ^ 1][l15 * 136 + 16 * w + 4 * quad] = hw;

// variant A (even waves): monolithic
#define DEC_STEP_A(T, RB)                                                            \
    do {                                                                             \
        DEC_HEAD(T, RB)                                                              \
        f32x4 acc[4];                                                                \
        _Pragma("unroll")                                                            \
        for (int typ = 0; typ < 4; typ++)                                            \
            acc[typ] = __builtin_amdgcn_mfma_f32_16x16x32_bf16(afrag[typ][0], bh[0], bias4[typ], 0, 0, 0); \
        _Pragma("unroll")                                                            \
        for (int kc = 1; kc < 4; kc++)                                               \
            _Pragma("unroll")                                                        \
            for (int typ = 0; typ < 4; typ++)                                        \
                acc[typ] = __builtin_amdgcn_mfma_f32_16x16x32_bf16(afrag[typ][kc], bh[kc], acc[typ], 0, 0, 0); \
        DEC_OUTPROJ(T)                                                               \
        float hh[4];                                                                 \
        _Pragma("unroll")                                                            \
        for (int r = 0; r < 4; r++) {                                                \
            float ii = sigmoid_f(acc[0][r]);                                         \
            float ff = sigmoid_f(acc[1][r]);                                         \
            float g2 = tanh_f(acc[2][r]);                                            \
            float oo = sigmoid_f(acc[3][r]);                                         \
            float cc = ff * cst[r] + ii * g2;                                        \
            cst[r] = cc;                                                             \
            hh[r] = oo * tanh_f(cc);                                                 \
        }                                                                            \
        DEC_TAIL(T, RB)                                                              \
    } while (0)

// variant B (odd waves): split gate-groups
#define DEC_STEP_B(T, RB)                                                            \
    do {                                                                             \
        DEC_HEAD(T, RB)                                                              \
        f32x4 a0 = __builtin_amdgcn_mfma_f32_16x16x32_bf16(afrag[0][0], bh[0], bias4[0], 0, 0, 0); \
        f32x4 a1 = __builtin_amdgcn_mfma_f32_16x16x32_bf16(afrag[1][0], bh[0], bias4[1], 0, 0, 0); \
        _Pragma("unroll")                                                            \
        for (int kc = 1; kc < 4; kc++) {                                             \
            a0 = __builtin_amdgcn_mfma_f32_16x16x32_bf16(afrag[0][kc], bh[kc], a0, 0, 0, 0); \
            a1 = __builtin_amdgcn_mfma_f32_16x16x32_bf16(afrag[1][kc], bh[kc], a1, 0, 0, 0); \
        }                                                                            \
        float e_i[4], e_f[4];                                                        \
        _Pragma("unroll")                                                            \
        for (int r = 0; r < 4; r++) {                                                \
            e_i[r] = exp2_f(a0[r] * L1C);                                            \
            e_f[r] = exp2_f(a1[r] * L1C);                                            \
        }                                                                            \
        f32x4 a2 = __builtin_amdgcn_mfma_f32_16x16x32_bf16(afrag[2][0], bh[0], bias4[2], 0, 0, 0); \
        f32x4 a3 = __builtin_amdgcn_mfma_f32_16x16x32_bf16(afrag[3][0], bh[0], bias4[3], 0, 0, 0); \
        _Pragma("unroll")                                                            \
        for (int kc = 1; kc < 4; kc++) {                                             \
            a2 = __builtin_amdgcn_mfma_f32_16x16x32_bf16(afrag[2][kc], bh[kc], a2, 0, 0, 0); \
            a3 = __builtin_amdgcn_mfma_f32_16x16x32_bf16(afrag[3][kc], bh[kc], a3, 0, 0, 0); \
        }                                                                            \
        DEC_OUTPROJ(T)                                                               \
        float e_g[4], e_o[4];                                                        \
        _Pragma("unroll")                                                            \
        for (int r = 0; r < 4; r++) {                                                \
            e_g[r] = exp2_f(a2[r] * L2C);                                            \
            e_o[r] = exp2_f(a3[r] * L1C);                                            \
        }                                                                            \
        float hh[4];                                                                 \
        _Pragma("unroll")                                                            \
        for (int r = 0; r < 4; r++) {                                                \
            float ii = __builtin_amdgcn_rcpf(1.f + e_i[r]);                          \
            float ff = __builtin_amdgcn_rcpf(1.f + e_f[r]);                          \
            float g2 = 1.f - 2.f * __builtin_amdgcn_rcpf(e_g[r] + 1.f);              \
            float oo = __builtin_amdgcn_rcpf(1.f + e_o[r]);                          \
            float cc = ff * cst[r] + ii * g2;                                        \
            cst[r] = cc;                                                             \
            hh[r] = oo * tanh_f(cc);                                                 \
        }                                                                            \
        DEC_TAIL(T, RB)                                                              \
    } while (0)

    if (w & 1) {
        for (int tp = 0; tp < 64; tp++) {
            DEC_STEP_B(2 * tp, 0);
            DEC_STEP_B(2 * tp + 1, 1);
        }
    } else {
        for (int tp = 0; tp < 64; tp++) {
            DEC_STEP_A(2 * tp, 0);
            DEC_STEP_A(2 * tp + 1, 1);
        }
    }
#undef DEC_STEP_A
#undef DEC_STEP_B
#undef DEC_HEAD
#undef DEC_OUTPROJ
#undef DEC_TAIL

    // o_127 from h_127 (t=127 wrote hS[0]); 128 & 7 == 0 -> wave 0, consistent with rotation
    LBAR();
    if (w == 0) {
        f32x4 accP = __builtin_amdgcn_mfma_f32_16x16x32_bf16(
            pfrag[0], *(const bf16x8*)&hS[0][l15 * 136 + 8 * quad], ob4, 0, 0, 0);
        #pragma unroll
        for (int kc = 1; kc < 4; kc++) {
            bf16x8 bh = *(const bf16x8*)&hS[0][l15 * 136 + 32 * kc + 8 * quad];
            accP = __builtin_amdgcn_mfma_f32_16x16x32_bf16(pfrag[kc], bh, accP, 0, 0, 0);
        }
        if (quad == 0)
            store_out(out, 520192 + (long)bown * NV + n, accP[0], obf);
    }
}

extern "C" void kernel_launch(void* const* d_in, const int* in_sizes, int n_in,
                              void* d_out, int out_size, void* d_ws, size_t ws_size,
                              hipStream_t stream) {
    char* ws = (char*)d_ws;
    float*    P    = (float*)(ws + 0);              // ~595 KB
    float*    Xc   = (float*)(ws + (1u << 20));     // 2 MB
    float*    C    = (float*)(ws + (3u << 20));     // 2 MB
    float*    qb   = (float*)(ws + (5u << 20));
    float*    kb   = (float*)(ws + (7u << 20));
    float*    vb   = (float*)(ws + (9u << 20));
    float*    Cst  = (float*)(ws + (11u << 20));

    Ptr19 a;
    for (int i = 0; i < 19; i++) a.p[i] = d_in[i];

    prep_kernel<<<842, 256, 0, stream>>>(a, P, Xc);
    enc_kernel<<<dim3(32, 8), 512, 0, stream>>>(Xc, d_in[2], P, C);
    qkv_kernel<<<dim3(128, 3), 256, 0, stream>>>(C, P, qb, kb, vb);
    attn_kernel<<<dim3(128, 2), 256, 0, stream>>>(qb, kb, vb, C, P, Cst, d_out);
    dec_kernel<<<dim3(32, 8), 512, 0, stream>>>(Cst, d_in[10], d_in[12], d_in[14], P, d_out);
}